// Round 1
// baseline (891.218 us; speedup 1.0000x reference)
//
#include <hip/hip_runtime.h>
#include <stdint.h>

// Shapes (fixed): B=4 L=2048 D=2048 H=16 KVH=4 HD=128 M=16 T=2032
typedef unsigned short u16;
typedef short s8v __attribute__((ext_vector_type(8)));   // 8 bf16 (4 VGPR) MFMA frag
typedef float f4v __attribute__((ext_vector_type(4)));   // MFMA accum

typedef __attribute__((address_space(1))) char gchar;
typedef __attribute__((address_space(3))) char lchar;

static __device__ __forceinline__ u16 f2bf(float f) {
  uint32_t x = __float_as_uint(f);
  x += 0x7fffu + ((x >> 16) & 1u);            // RNE
  return (u16)(x >> 16);
}
static __device__ __forceinline__ float bf2f(u16 u) {
  return __uint_as_float(((uint32_t)u) << 16);
}
// async global->LDS, 16B per lane. LDS dest must be wave-linear (base + lane*16).
static __device__ __forceinline__ void gload_lds16(const void* g, void* l) {
  __builtin_amdgcn_global_load_lds((gchar*)(uintptr_t)g,
                                   (lchar*)(uint32_t)(uintptr_t)l, 16, 0, 0);
}

// ---------------- fp32 -> bf16 convert (vectorized) ----------------
__global__ __launch_bounds__(256) void cvt_bf16(const float4* __restrict__ src,
                                                uint2* __restrict__ dst, int n4) {
  int i = blockIdx.x * 256 + threadIdx.x;
  int st = gridDim.x * 256;
  for (; i < n4; i += st) {
    float4 v = src[i];
    uint2 o;
    o.x = (uint32_t)f2bf(v.x) | ((uint32_t)f2bf(v.y) << 16);
    o.y = (uint32_t)f2bf(v.z) | ((uint32_t)f2bf(v.w) << 16);
    dst[i] = o;
  }
}

// ---------------- RoPE cos/sin table: [T=2032][64] ----------------
__global__ __launch_bounds__(256) void rope_table(float* __restrict__ tc,
                                                  float* __restrict__ ts) {
  int i = blockIdx.x * 256 + threadIdx.x;
  if (i >= 2032 * 64) return;
  int t = i >> 6, f = i & 63;
  float invf = 1.0f / powf(10000.0f, (float)f * (1.0f / 64.0f)); // accurate powf
  float ang = (float)t * invf;
  float s, c;
  sincosf(ang, &s, &c);                                           // accurate sincos
  tc[i] = c;
  ts[i] = s;
}

// ---------------- NT GEMM core: C = A(MxK) @ W(NxK)^T, bf16 in, 128x128 tile, BK=64
// MODE 0: QKV -> bf16 outputs scattered to (B,heads,L,HD). MODE 1: proj -> fp32 out.
template <int MODE>
__global__ __launch_bounds__(256) void gemm_nt(
    const u16* __restrict__ A, const u16* __restrict__ W0,
    const u16* __restrict__ W1, const u16* __restrict__ W2,
    u16* __restrict__ O0, u16* __restrict__ O1, u16* __restrict__ O2,
    float* __restrict__ OF) {
  __shared__ u16 lA[128 * 64];
  __shared__ u16 lB[128 * 64];
  const int tid = threadIdx.x;
  const int lane = tid & 63, wid = tid >> 6;
  const int wr = wid >> 1, wc = wid & 1;
  const int l15 = lane & 15, l4 = lane >> 4;
  const int m0 = blockIdx.x * 128;
  const int bn = blockIdx.y;

  const u16* Wt;
  int nrow0;
  if constexpr (MODE == 0) {
    if (bn < 16)      { Wt = W0; nrow0 = bn * 128; }
    else if (bn < 20) { Wt = W1; nrow0 = (bn - 16) * 128; }
    else              { Wt = W2; nrow0 = (bn - 20) * 128; }
  } else {
    Wt = W0; nrow0 = bn * 128;
  }

  const f4v Z4 = {0.f, 0.f, 0.f, 0.f};
  f4v acc[4][4];
#pragma unroll
  for (int i = 0; i < 4; i++)
#pragma unroll
    for (int j = 0; j < 4; j++) acc[i][j] = Z4;

  for (int kb = 0; kb < 2048; kb += 64) {
    __syncthreads();
#pragma unroll
    for (int j = 0; j < 4; ++j) {           // stage A: 128x64 bf16 = 16KB
      int slot = j * 256 + tid;
      int row = slot >> 3, c8 = (slot & 7) * 8;
      gload_lds16(A + (m0 + row) * 2048 + kb + c8, &lA[slot * 8]);
    }
#pragma unroll
    for (int j = 0; j < 4; ++j) {           // stage B
      int slot = j * 256 + tid;
      int row = slot >> 3, c8 = (slot & 7) * 8;
      gload_lds16(Wt + (nrow0 + row) * 2048 + kb + c8, &lB[slot * 8]);
    }
    __syncthreads();
#pragma unroll
    for (int ks = 0; ks < 2; ++ks) {
      s8v af[4], bfr[4];
#pragma unroll
      for (int i = 0; i < 4; i++)
        af[i] = *(const s8v*)&lA[(wr * 64 + i * 16 + l15) * 64 + ks * 32 + l4 * 8];
#pragma unroll
      for (int j = 0; j < 4; j++)
        bfr[j] = *(const s8v*)&lB[(wc * 64 + j * 16 + l15) * 64 + ks * 32 + l4 * 8];
#pragma unroll
      for (int i = 0; i < 4; i++)
#pragma unroll
        for (int j = 0; j < 4; j++)
          acc[i][j] = __builtin_amdgcn_mfma_f32_16x16x32_bf16(af[i], bfr[j], acc[i][j], 0, 0, 0);
    }
  }

  if constexpr (MODE == 0) {
    u16* Ob; int hh, HX;
    if (bn < 16)      { Ob = O0; hh = bn;      HX = 16; }
    else if (bn < 20) { Ob = O1; hh = bn - 16; HX = 4; }
    else              { Ob = O2; hh = bn - 20; HX = 4; }
#pragma unroll
    for (int i = 0; i < 4; i++)
#pragma unroll
      for (int r = 0; r < 4; r++) {
        int m = m0 + wr * 64 + i * 16 + l4 * 4 + r;
        int b = m >> 11, l = m & 2047;
        int base = ((b * HX + hh) * 2048 + l) * 128;   // (B,HX,L,128)
#pragma unroll
        for (int j = 0; j < 4; j++) {
          int d = wc * 64 + j * 16 + l15;
          Ob[base + d] = f2bf(acc[i][j][r]);
        }
      }
  } else {
#pragma unroll
    for (int i = 0; i < 4; i++)
#pragma unroll
      for (int r = 0; r < 4; r++) {
        int m = m0 + wr * 64 + i * 16 + l4 * 4 + r;
#pragma unroll
        for (int j = 0; j < 4; j++) {
          int n = bn * 128 + wc * 64 + j * 16 + l15;
          OF[(size_t)m * 2048 + n] = acc[i][j][r];
        }
      }
  }
}

// ---------------- RMSNorm + RoPE + gain, in place, one wave per 128-wide row
__global__ __launch_bounds__(256) void norm_rope(u16* __restrict__ buf, int nh,
                                                 const float* __restrict__ gain,
                                                 const float* __restrict__ tc,
                                                 const float* __restrict__ ts,
                                                 int nrows) {
  const int lane = threadIdx.x & 63;
  const int gw = blockIdx.x * 4 + (threadIdx.x >> 6);
  const int nw = gridDim.x * 4;
  for (int row = gw; row < nrows; row += nw) {
    int l = row & 2047;
    int h = (row >> 11) % nh;
    u16* p = buf + (size_t)row * 128;
    float x1 = bf2f(p[lane]);
    float x2 = bf2f(p[lane + 64]);
    float ss = x1 * x1 + x2 * x2;
#pragma unroll
    for (int off = 32; off > 0; off >>= 1) ss += __shfl_xor(ss, off, 64);
    float r = rsqrtf(ss * (1.0f / 128.0f) + 1.1920929e-07f);
    x1 *= r; x2 *= r;
    if (l >= 16) {
      int t = l - 16;
      float c = tc[t * 64 + lane], s = ts[t * 64 + lane];
      float o1 = x1 * c + x2 * s;
      float o2 = -x1 * s + x2 * c;
      x1 = o1; x2 = o2;
    }
    if (gain) { float g = gain[h]; x1 *= g; x2 *= g; }
    p[lane] = f2bf(x1);
    p[lane + 64] = f2bf(x2);
  }
}

// ---------------- V transpose: (bg,L,128) -> (bg,128,L), 64x64 LDS tiles, XOR swizzle
__global__ __launch_bounds__(256) void transpose_v(const u16* __restrict__ v,
                                                   u16* __restrict__ vt) {
  __shared__ u16 t[64][64];
  const int l0 = blockIdx.x * 64, d0 = blockIdx.y * 64, bg = blockIdx.z;
  const int tid = threadIdx.x;
#pragma unroll
  for (int it = 0; it < 2; ++it) {
    int lin = it * 256 + tid;
    int r = lin >> 3, cb = lin & 7;
    s8v val = *(const s8v*)&v[((bg * 2048 + l0 + r) * 128) + d0 + cb * 8];
    *(s8v*)&t[r][(cb ^ (r & 7)) * 8] = val;
  }
  __syncthreads();
#pragma unroll
  for (int it = 0; it < 2; ++it) {
    int lin = it * 256 + tid;
    int r2 = lin >> 3, c2 = (lin & 7) * 8;   // r2 = d idx, c2 = l idx
    s8v o;
#pragma unroll
    for (int j = 0; j < 8; ++j) {
      int rr = c2 + j, cc = r2;
      o[j] = (short)t[rr][(cc & 7) + 8 * ((cc >> 3) ^ (rr & 7))];
    }
    *(s8v*)&vt[((bg * 128 + d0 + r2) * 2048) + l0 + c2] = o;
  }
}

// ---------------- flash attention: block = 4 waves = 4 q-heads of one KV group
// each wave: 32 q-rows; KVBLK=32; online softmax fp32; P via per-wave LDS roundtrip
__global__ __launch_bounds__(256) void attn(const u16* __restrict__ q,
                                            const u16* __restrict__ k,
                                            const u16* __restrict__ vt,
                                            u16* __restrict__ y) {
  __shared__ u16 lK[32 * 128];     // row kj: 16 slots of 16B, slot s holds d-block (s^(kj&7))
  __shared__ u16 lVT[128 * 32];    // [d][kj] linear
  __shared__ u16 lP[4][16 * 32];   // per-wave P tile
  const int tid = threadIdx.x;
  const int lane = tid & 63, wid = tid >> 6;
  const int l15 = lane & 15, l4 = lane >> 4;
  const int qt = (int)gridDim.x - 1 - (int)blockIdx.x;  // heavy blocks first
  const int byy = blockIdx.y;
  const int b = byy >> 2, g = byy & 3;
  const int h = g * 4 + wid;
  const int q0 = qt * 32;

  // Q fragments straight from global (post-norm q)
  const u16* qp = q + ((b * 16 + h) * 2048 + q0) * 128;
  s8v qf[2][4];
#pragma unroll
  for (int mi = 0; mi < 2; ++mi)
#pragma unroll
    for (int ks = 0; ks < 4; ++ks)
      qf[mi][ks] = *(const s8v*)&qp[(mi * 16 + l15) * 128 + ks * 32 + l4 * 8];

  const f4v Z4 = {0.f, 0.f, 0.f, 0.f};
  f4v yacc[2][8];
#pragma unroll
  for (int mi = 0; mi < 2; mi++)
#pragma unroll
    for (int nj = 0; nj < 8; nj++) yacc[mi][nj] = Z4;
  float mrow[2][4], lrow[2][4];
#pragma unroll
  for (int mi = 0; mi < 2; mi++)
#pragma unroll
    for (int r = 0; r < 4; r++) { mrow[mi][r] = -1e30f; lrow[mi][r] = 0.f; }

  const u16* kb0 = k + (b * 4 + g) * 2048 * 128;
  const u16* vb0 = vt + (b * 4 + g) * 128 * 2048;
  const float scale = 0.08838834764831845f;  // 1/sqrt(128)

  for (int tkv = 0; tkv <= qt; ++tkv) {
    const int kv0 = tkv * 32;
    __syncthreads();
#pragma unroll
    for (int it = 0; it < 2; ++it) {         // K tile 32x128, swizzled source
      int slot = it * 256 + tid;
      int kj = slot >> 4, s = slot & 15;
      gload_lds16(kb0 + (kv0 + kj) * 128 + (s ^ (kj & 7)) * 8, &lK[slot * 8]);
    }
#pragma unroll
    for (int it = 0; it < 2; ++it) {         // VT tile 128x32, linear
      int slot = it * 256 + tid;
      int d = slot >> 2, s = slot & 3;
      gload_lds16(vb0 + d * 2048 + kv0 + s * 8, &lVT[slot * 8]);
    }
    __syncthreads();

    s8v vf[8];
#pragma unroll
    for (int nj = 0; nj < 8; nj++)
      vf[nj] = *(const s8v*)&lVT[(nj * 16 + l15) * 32 + l4 * 8];

    const bool domask = (tkv == qt);
#pragma unroll
    for (int mi = 0; mi < 2; ++mi) {
      f4v sa[2]; sa[0] = Z4; sa[1] = Z4;
#pragma unroll
      for (int grp = 0; grp < 2; ++grp)
#pragma unroll
        for (int ks = 0; ks < 4; ++ks) {
          int kj = grp * 16 + l15;
          int dblk = ks * 4 + l4;
          s8v kf = *(const s8v*)&lK[(kj * 16 + (dblk ^ (kj & 7))) * 8];
          sa[grp] = __builtin_amdgcn_mfma_f32_16x16x32_bf16(qf[mi][ks], kf, sa[grp], 0, 0, 0);
        }
      float sv[2][4];
#pragma unroll
      for (int grp = 0; grp < 2; ++grp)
#pragma unroll
        for (int r = 0; r < 4; r++) {
          float s = sa[grp][r] * scale;
          if (domask && (kv0 + grp * 16 + l15) > (q0 + mi * 16 + l4 * 4 + r)) s = -1e30f;
          sv[grp][r] = s;
        }
#pragma unroll
      for (int r = 0; r < 4; r++) {
        float mx = fmaxf(sv[0][r], sv[1][r]);
#pragma unroll
        for (int off = 8; off > 0; off >>= 1) mx = fmaxf(mx, __shfl_xor(mx, off, 64));
        float mnew = fmaxf(mrow[mi][r], mx);
        float corr = __expf(mrow[mi][r] - mnew);
        mrow[mi][r] = mnew;
        u16 b0 = f2bf(__expf(sv[0][r] - mnew));
        u16 b1 = f2bf(__expf(sv[1][r] - mnew));
        lP[wid][(l4 * 4 + r) * 32 + l15] = b0;
        lP[wid][(l4 * 4 + r) * 32 + 16 + l15] = b1;
        float ps = bf2f(b0) + bf2f(b1);      // denom matches bf16 numerator
#pragma unroll
        for (int off = 8; off > 0; off >>= 1) ps += __shfl_xor(ps, off, 64);
        lrow[mi][r] = lrow[mi][r] * corr + ps;
#pragma unroll
        for (int nj = 0; nj < 8; nj++) yacc[mi][nj][r] *= corr;
      }
      s8v pa = *(const s8v*)&lP[wid][l15 * 32 + l4 * 8];
#pragma unroll
      for (int nj = 0; nj < 8; nj++)
        yacc[mi][nj] = __builtin_amdgcn_mfma_f32_16x16x32_bf16(pa, vf[nj], yacc[mi][nj], 0, 0, 0);
    }
  }

#pragma unroll
  for (int mi = 0; mi < 2; mi++)
#pragma unroll
    for (int r = 0; r < 4; r++) {
      int row = q0 + mi * 16 + l4 * 4 + r;
      float inv = 1.0f / lrow[mi][r];
      int base = (b * 2048 + row) * 2048 + h * 128;   // y: (B,L,H*HD) bf16
#pragma unroll
      for (int nj = 0; nj < 8; nj++)
        y[(size_t)base + nj * 16 + l15] = f2bf(yacc[mi][nj][r] * inv);
    }
}

extern "C" void kernel_launch(void* const* d_in, const int* in_sizes, int n_in,
                              void* d_out, int out_size, void* d_ws, size_t ws_size,
                              hipStream_t stream) {
  const float* x  = (const float*)d_in[0];
  const float* Wq = (const float*)d_in[1];
  const float* Wk = (const float*)d_in[2];
  const float* Wv = (const float*)d_in[3];
  const float* Wp = (const float*)d_in[4];
  const float* qg = (const float*)d_in[5];
  float* out = (float*)d_out;

  char* ws = (char*)d_ws;
  size_t off = 0;
  auto alloc = [&](size_t bytes) {
    void* p = ws + off;
    off += (bytes + 255) & ~(size_t)255;
    return p;
  };
  u16* x_bf  = (u16*)alloc((size_t)8192 * 2048 * 2);   // also reused as y_bf
  u16* wq_bf = (u16*)alloc((size_t)2048 * 2048 * 2);   // also reused as vt_bf
  u16* wk_bf = (u16*)alloc((size_t)512 * 2048 * 2);
  u16* wv_bf = (u16*)alloc((size_t)512 * 2048 * 2);
  u16* wp_bf = (u16*)alloc((size_t)2048 * 2048 * 2);
  u16* q_bf  = (u16*)alloc((size_t)4 * 16 * 2048 * 128 * 2);
  u16* k_bf  = (u16*)alloc((size_t)4 * 4 * 2048 * 128 * 2);
  u16* v_bf  = (u16*)alloc((size_t)4 * 4 * 2048 * 128 * 2);
  float* tab = (float*)alloc((size_t)2032 * 64 * 2 * 4);
  u16* y_bf  = x_bf;    // x dead after QKV GEMM
  u16* vt_bf = wq_bf;   // Wq dead after QKV GEMM (same size)

  cvt_bf16<<<2048, 256, 0, stream>>>((const float4*)x,  (uint2*)x_bf,  8192 * 2048 / 4);
  cvt_bf16<<<512,  256, 0, stream>>>((const float4*)Wq, (uint2*)wq_bf, 2048 * 2048 / 4);
  cvt_bf16<<<128,  256, 0, stream>>>((const float4*)Wk, (uint2*)wk_bf, 512 * 2048 / 4);
  cvt_bf16<<<128,  256, 0, stream>>>((const float4*)Wv, (uint2*)wv_bf, 512 * 2048 / 4);
  cvt_bf16<<<512,  256, 0, stream>>>((const float4*)Wp, (uint2*)wp_bf, 2048 * 2048 / 4);
  rope_table<<<(2032 * 64 + 255) / 256, 256, 0, stream>>>(tab, tab + 2032 * 64);

  gemm_nt<0><<<dim3(64, 24), 256, 0, stream>>>(x_bf, wq_bf, wk_bf, wv_bf,
                                               q_bf, k_bf, v_bf, nullptr);
  norm_rope<<<2048, 256, 0, stream>>>(q_bf, 16, qg, tab, tab + 2032 * 64, 4 * 16 * 2048);
  norm_rope<<<512,  256, 0, stream>>>(k_bf, 4, nullptr, tab, tab + 2032 * 64, 4 * 4 * 2048);
  transpose_v<<<dim3(32, 2, 16), 256, 0, stream>>>(v_bf, vt_bf);
  attn<<<dim3(64, 16), 256, 0, stream>>>(q_bf, k_bf, vt_bf, y_bf);
  gemm_nt<1><<<dim3(64, 16), 256, 0, stream>>>(y_bf, wp_bf, nullptr, nullptr,
                                               nullptr, nullptr, nullptr, out);
}

// Round 2
// 452.016 us; speedup vs baseline: 1.9717x; 1.9717x over previous
//
#include <hip/hip_runtime.h>
#include <stdint.h>

// Shapes (fixed): B=4 L=2048 D=2048 H=16 KVH=4 HD=128 M=16 T=2032
typedef unsigned short u16;
typedef short s8v __attribute__((ext_vector_type(8)));   // 8 bf16 (4 VGPR) MFMA frag
typedef float f4v __attribute__((ext_vector_type(4)));   // 16x16 MFMA accum
typedef float f16v __attribute__((ext_vector_type(16))); // 32x32 MFMA accum

typedef __attribute__((address_space(1))) char gchar;
typedef __attribute__((address_space(3))) char lchar;

static __device__ __forceinline__ u16 f2bf(float f) {
  uint32_t x = __float_as_uint(f);
  x += 0x7fffu + ((x >> 16) & 1u);            // RNE
  return (u16)(x >> 16);
}
static __device__ __forceinline__ float bf2f(u16 u) {
  return __uint_as_float(((uint32_t)u) << 16);
}
// async global->LDS, 16B per lane. LDS dest must be wave-linear (base + lane*16).
static __device__ __forceinline__ void gload_lds16(const void* g, void* l) {
  __builtin_amdgcn_global_load_lds((gchar*)(uintptr_t)g,
                                   (lchar*)(uint32_t)(uintptr_t)l, 16, 0, 0);
}

// ---------------- fp32 -> bf16 convert (vectorized) ----------------
__global__ __launch_bounds__(256) void cvt_bf16(const float4* __restrict__ src,
                                                uint2* __restrict__ dst, int n4) {
  int i = blockIdx.x * 256 + threadIdx.x;
  int st = gridDim.x * 256;
  for (; i < n4; i += st) {
    float4 v = src[i];
    uint2 o;
    o.x = (uint32_t)f2bf(v.x) | ((uint32_t)f2bf(v.y) << 16);
    o.y = (uint32_t)f2bf(v.z) | ((uint32_t)f2bf(v.w) << 16);
    dst[i] = o;
  }
}

// ---------------- RoPE cos/sin table: [T=2032][64] ----------------
__global__ __launch_bounds__(256) void rope_table(float* __restrict__ tc,
                                                  float* __restrict__ ts) {
  int i = blockIdx.x * 256 + threadIdx.x;
  if (i >= 2032 * 64) return;
  int t = i >> 6, f = i & 63;
  float invf = 1.0f / powf(10000.0f, (float)f * (1.0f / 64.0f)); // accurate powf
  float ang = (float)t * invf;
  float s, c;
  sincosf(ang, &s, &c);                                           // accurate sincos
  tc[i] = c;
  ts[i] = s;
}

// ---------------- NT GEMM core: C = A(MxK) @ W(NxK)^T, bf16 in, 128x128 tile, BK=64
// MODE 0: QKV -> bf16 outputs scattered to (B,heads,L,HD). MODE 1: proj -> fp32 out.
template <int MODE>
__global__ __launch_bounds__(256) void gemm_nt(
    const u16* __restrict__ A, const u16* __restrict__ W0,
    const u16* __restrict__ W1, const u16* __restrict__ W2,
    u16* __restrict__ O0, u16* __restrict__ O1, u16* __restrict__ O2,
    float* __restrict__ OF) {
  __shared__ u16 lA[128 * 64];
  __shared__ u16 lB[128 * 64];
  const int tid = threadIdx.x;
  const int lane = tid & 63, wid = tid >> 6;
  const int wr = wid >> 1, wc = wid & 1;
  const int l15 = lane & 15, l4 = lane >> 4;
  const int m0 = blockIdx.x * 128;
  const int bn = blockIdx.y;

  const u16* Wt;
  int nrow0;
  if constexpr (MODE == 0) {
    if (bn < 16)      { Wt = W0; nrow0 = bn * 128; }
    else if (bn < 20) { Wt = W1; nrow0 = (bn - 16) * 128; }
    else              { Wt = W2; nrow0 = (bn - 20) * 128; }
  } else {
    Wt = W0; nrow0 = bn * 128;
  }

  const f4v Z4 = {0.f, 0.f, 0.f, 0.f};
  f4v acc[4][4];
#pragma unroll
  for (int i = 0; i < 4; i++)
#pragma unroll
    for (int j = 0; j < 4; j++) acc[i][j] = Z4;

  for (int kb = 0; kb < 2048; kb += 64) {
    __syncthreads();
#pragma unroll
    for (int j = 0; j < 4; ++j) {           // stage A: 128x64 bf16 = 16KB
      int slot = j * 256 + tid;
      int row = slot >> 3, c8 = (slot & 7) * 8;
      gload_lds16(A + (m0 + row) * 2048 + kb + c8, &lA[slot * 8]);
    }
#pragma unroll
    for (int j = 0; j < 4; ++j) {           // stage B
      int slot = j * 256 + tid;
      int row = slot >> 3, c8 = (slot & 7) * 8;
      gload_lds16(Wt + (nrow0 + row) * 2048 + kb + c8, &lB[slot * 8]);
    }
    __syncthreads();
#pragma unroll
    for (int ks = 0; ks < 2; ++ks) {
      s8v af[4], bfr[4];
#pragma unroll
      for (int i = 0; i < 4; i++)
        af[i] = *(const s8v*)&lA[(wr * 64 + i * 16 + l15) * 64 + ks * 32 + l4 * 8];
#pragma unroll
      for (int j = 0; j < 4; j++)
        bfr[j] = *(const s8v*)&lB[(wc * 64 + j * 16 + l15) * 64 + ks * 32 + l4 * 8];
#pragma unroll
      for (int i = 0; i < 4; i++)
#pragma unroll
        for (int j = 0; j < 4; j++)
          acc[i][j] = __builtin_amdgcn_mfma_f32_16x16x32_bf16(af[i], bfr[j], acc[i][j], 0, 0, 0);
    }
  }

  if constexpr (MODE == 0) {
    u16* Ob; int hh, HX;
    if (bn < 16)      { Ob = O0; hh = bn;      HX = 16; }
    else if (bn < 20) { Ob = O1; hh = bn - 16; HX = 4; }
    else              { Ob = O2; hh = bn - 20; HX = 4; }
#pragma unroll
    for (int i = 0; i < 4; i++)
#pragma unroll
      for (int r = 0; r < 4; r++) {
        int m = m0 + wr * 64 + i * 16 + l4 * 4 + r;
        int b = m >> 11, l = m & 2047;
        int base = ((b * HX + hh) * 2048 + l) * 128;   // (B,HX,L,128)
#pragma unroll
        for (int j = 0; j < 4; j++) {
          int d = wc * 64 + j * 16 + l15;
          Ob[base + d] = f2bf(acc[i][j][r]);
        }
      }
  } else {
#pragma unroll
    for (int i = 0; i < 4; i++)
#pragma unroll
      for (int r = 0; r < 4; r++) {
        int m = m0 + wr * 64 + i * 16 + l4 * 4 + r;
#pragma unroll
        for (int j = 0; j < 4; j++) {
          int n = bn * 128 + wc * 64 + j * 16 + l15;
          OF[(size_t)m * 2048 + n] = acc[i][j][r];
        }
      }
  }
}

// ---------------- RMSNorm + RoPE + gain, in place, one wave per 128-wide row
__global__ __launch_bounds__(256) void norm_rope(u16* __restrict__ buf, int nh,
                                                 const float* __restrict__ gain,
                                                 const float* __restrict__ tc,
                                                 const float* __restrict__ ts,
                                                 int nrows) {
  const int lane = threadIdx.x & 63;
  const int gw = blockIdx.x * 4 + (threadIdx.x >> 6);
  const int nw = gridDim.x * 4;
  for (int row = gw; row < nrows; row += nw) {
    int l = row & 2047;
    int h = (row >> 11) % nh;
    u16* p = buf + (size_t)row * 128;
    float x1 = bf2f(p[lane]);
    float x2 = bf2f(p[lane + 64]);
    float ss = x1 * x1 + x2 * x2;
#pragma unroll
    for (int off = 32; off > 0; off >>= 1) ss += __shfl_xor(ss, off, 64);
    float r = rsqrtf(ss * (1.0f / 128.0f) + 1.1920929e-07f);
    x1 *= r; x2 *= r;
    if (l >= 16) {
      int t = l - 16;
      float c = tc[t * 64 + lane], s = ts[t * 64 + lane];
      float o1 = x1 * c + x2 * s;
      float o2 = -x1 * s + x2 * c;
      x1 = o1; x2 = o2;
    }
    if (gain) { float g = gain[h]; x1 *= g; x2 *= g; }
    p[lane] = f2bf(x1);
    p[lane + 64] = f2bf(x2);
  }
}

// ---------------- V transpose: (bg,L,128) -> (bg,128,L), 64x64 LDS tiles, XOR swizzle
__global__ __launch_bounds__(256) void transpose_v(const u16* __restrict__ v,
                                                   u16* __restrict__ vt) {
  __shared__ u16 t[64][64];
  const int l0 = blockIdx.x * 64, d0 = blockIdx.y * 64, bg = blockIdx.z;
  const int tid = threadIdx.x;
#pragma unroll
  for (int it = 0; it < 2; ++it) {
    int lin = it * 256 + tid;
    int r = lin >> 3, cb = lin & 7;
    s8v val = *(const s8v*)&v[((bg * 2048 + l0 + r) * 128) + d0 + cb * 8];
    *(s8v*)&t[r][(cb ^ (r & 7)) * 8] = val;
  }
  __syncthreads();
#pragma unroll
  for (int it = 0; it < 2; ++it) {
    int lin = it * 256 + tid;
    int r2 = lin >> 3, c2 = (lin & 7) * 8;   // r2 = d idx, c2 = l idx
    s8v o;
#pragma unroll
    for (int j = 0; j < 8; ++j) {
      int rr = c2 + j, cc = r2;
      o[j] = (short)t[rr][(cc & 7) + 8 * ((cc >> 3) ^ (rr & 7))];
    }
    *(s8v*)&vt[((bg * 128 + d0 + r2) * 2048) + l0 + c2] = o;
  }
}

// ---------------- flash attention, 32x32 swapped-QK^T structure ----------------
// block = 4 waves = 4 q-heads of one KV group, 32 q-rows each; KVBLK=64.
// Causal pairing: block i handles q-tiles {i, 63-i} -> uniform 33-34 KV iters.
// Swapped QK^T (mfma(K,Q) -> C[kv][q]): lane owns q-row (lane&31); softmax fully
// in-register; P->PV A-frag rebuilt via bf16 pack + shfl_xor(32); defer-max THR=8.
__global__ __launch_bounds__(256, 2) void attn(const u16* __restrict__ q,
                                               const u16* __restrict__ k,
                                               const u16* __restrict__ vt,
                                               u16* __restrict__ y) {
  __shared__ u16 lK[2][64 * 128];   // row kv: 16 slots of 8 u16, slot s holds d-block s^(kv&7)
  __shared__ u16 lVT[2][128 * 64];  // row d:   8 slots of 8 u16, slot s holds kv-block s^(d&7)
  const int tid = threadIdx.x;
  const int lane = tid & 63, wid = tid >> 6;
  const int l31 = lane & 31, hi = lane >> 5;

  // XCD-aware remap: all 32 pair-blocks of one (b,g) land on one XCD (KV panel in L2)
  const int db = (int)blockIdx.y * 32 + (int)blockIdx.x;  // 0..511
  const int half = db >> 8, rem = db & 255;
  const int bg = (rem & 7) + 8 * half;                    // 0..15
  const int pairi = rem >> 3;                             // 0..31
  const int b = bg >> 2, g = bg & 3;
  const int h = g * 4 + wid;

  const u16* qh = q + (size_t)(b * 16 + h) * 2048 * 128;
  const u16* kb0 = k + (size_t)(b * 4 + g) * 2048 * 128;
  const u16* vtb0 = vt + (size_t)(b * 4 + g) * 128 * 2048;
  const float scale = 0.08838834764831845f;  // 1/sqrt(128)

  auto stage = [&](int t, int bufsel) {
    const int kv0 = t * 64;
#pragma unroll
    for (int it = 0; it < 4; ++it) {        // K tile 64x128 (16KB), swizzled source
      int lin = it * 256 + tid;
      int kj = lin >> 4, s = lin & 15;
      gload_lds16(kb0 + (size_t)(kv0 + kj) * 128 + ((s ^ (kj & 7)) * 8),
                  &lK[bufsel][lin * 8]);
    }
#pragma unroll
    for (int it = 0; it < 4; ++it) {        // VT tile 128x64 (16KB), swizzled source
      int lin = it * 256 + tid;
      int d = lin >> 3, s = lin & 7;
      gload_lds16(vtb0 + (size_t)d * 2048 + kv0 + ((s ^ (d & 7)) * 8),
                  &lVT[bufsel][lin * 8]);
    }
  };

  for (int ph = 0; ph < 2; ++ph) {
    const int qt = ph ? (63 - pairi) : pairi;
    const int q0 = qt * 32;
    const int nt = (q0 >> 6) + 1;           // KV tiles of 64 covering [0, q0+32)
    const int qabs = q0 + l31;

    // Q fragments: B-operand, col=q (lane&31), k = d = ks*16 + 8*hi + jj
    s8v qf[8];
#pragma unroll
    for (int ks = 0; ks < 8; ++ks)
      qf[ks] = *(const s8v*)&qh[(q0 + l31) * 128 + ks * 16 + hi * 8];

    f16v yacc[4];
#pragma unroll
    for (int j = 0; j < 4; ++j)
#pragma unroll
      for (int r = 0; r < 16; ++r) yacc[j][r] = 0.f;
    float mrow = -1e30f, lrow = 0.f;

    stage(0, 0);
    __syncthreads();

    for (int t = 0; t < nt; ++t) {
      const int cur = t & 1;
      if (t + 1 < nt) stage(t + 1, cur ^ 1);
      const int kv0 = t * 64;

      // ---- QK^T swapped: S^T[kv][q], two 32-kv chunks ----
      f16v s0a, s1a;
#pragma unroll
      for (int r = 0; r < 16; ++r) { s0a[r] = 0.f; s1a[r] = 0.f; }
#pragma unroll
      for (int ks = 0; ks < 8; ++ks) {
        const int slot = (2 * ks + hi) ^ (l31 & 7);
        s8v kf0 = *(const s8v*)&lK[cur][(l31)*128 + slot * 8];
        s8v kf1 = *(const s8v*)&lK[cur][(32 + l31) * 128 + slot * 8];
        s0a = __builtin_amdgcn_mfma_f32_32x32x16_bf16(kf0, qf[ks], s0a, 0, 0, 0);
        s1a = __builtin_amdgcn_mfma_f32_32x32x16_bf16(kf1, qf[ks], s1a, 0, 0, 0);
      }

      // ---- scale + causal mask + row max (in-register) ----
      const bool last = (t == nt - 1);
      float p0[16], p1[16];
      float pmax = -1e30f;
#pragma unroll
      for (int r = 0; r < 16; ++r) {
        const int kvloc = (r & 3) + 8 * (r >> 2) + 4 * hi;
        float v0 = s0a[r] * scale;
        float v1 = s1a[r] * scale;
        if (last) {
          if (kv0 + kvloc > qabs) v0 = -1e30f;
          if (kv0 + 32 + kvloc > qabs) v1 = -1e30f;
        }
        p0[r] = v0; p1[r] = v1;
        pmax = fmaxf(pmax, fmaxf(v0, v1));
      }
      pmax = fmaxf(pmax, __shfl_xor(pmax, 32, 64));

      // ---- defer-max (T13): rescale only when max grows past THR=8 ----
      if (!__all(pmax - mrow <= 8.0f)) {
        float mnew = fmaxf(mrow, pmax);
        float corr = __expf(mrow - mnew);
#pragma unroll
        for (int r = 0; r < 16; ++r) {
          const int qloc = (r & 3) + 8 * (r >> 2) + 4 * hi;
          float cb = __shfl(corr, qloc, 64);
          yacc[0][r] *= cb; yacc[1][r] *= cb; yacc[2][r] *= cb; yacc[3][r] *= cb;
        }
        lrow *= corr;
        mrow = mnew;
      }

      // ---- exp (bf16-rounded so denom matches MFMA numerator) + row sum ----
      float ps = 0.f;
#pragma unroll
      for (int r = 0; r < 16; ++r) {
        float e0 = bf2f(f2bf(__expf(p0[r] - mrow)));
        float e1 = bf2f(f2bf(__expf(p1[r] - mrow)));
        p0[r] = e0; p1[r] = e1;
        ps += e0 + e1;
      }
      ps += __shfl_xor(ps, 32, 64);
      lrow += ps;

      // ---- PV: rebuild A-frag (P rows = q) via pack + half-wave exchange ----
#pragma unroll
      for (int ks = 0; ks < 4; ++ks) {
        const float* pc = (ks < 2) ? p0 : p1;
        const int rb = 8 * (ks & 1);
        uint32_t A0 = (uint32_t)f2bf(pc[rb + 0]) | ((uint32_t)f2bf(pc[rb + 1]) << 16);
        uint32_t A1 = (uint32_t)f2bf(pc[rb + 2]) | ((uint32_t)f2bf(pc[rb + 3]) << 16);
        uint32_t B0 = (uint32_t)f2bf(pc[rb + 4]) | ((uint32_t)f2bf(pc[rb + 5]) << 16);
        uint32_t B1 = (uint32_t)f2bf(pc[rb + 6]) | ((uint32_t)f2bf(pc[rb + 7]) << 16);
        uint32_t t0 = hi ? A0 : B0;
        uint32_t t1 = hi ? A1 : B1;
        uint32_t r0 = (uint32_t)__shfl_xor((int)t0, 32, 64);
        uint32_t r1 = (uint32_t)__shfl_xor((int)t1, 32, 64);
        union { uint32_t u[4]; s8v v; } uu;
        uu.u[0] = hi ? r0 : A0;
        uu.u[1] = hi ? r1 : A1;
        uu.u[2] = hi ? B0 : r0;
        uu.u[3] = hi ? B1 : r1;
#pragma unroll
        for (int jd = 0; jd < 4; ++jd) {
          const int rowd = 32 * jd + l31;
          const int slot = (2 * ks + hi) ^ (l31 & 7);
          s8v vf = *(const s8v*)&lVT[cur][rowd * 64 + slot * 8];
          yacc[jd] = __builtin_amdgcn_mfma_f32_32x32x16_bf16(uu.v, vf, yacc[jd], 0, 0, 0);
        }
      }
      __syncthreads();
    }

    // ---- finalize: broadcast 1/l per C-row, write y (B,L,H*128) bf16 ----
    float inv = 1.0f / lrow;
#pragma unroll
    for (int r = 0; r < 16; ++r) {
      const int qloc = (r & 3) + 8 * (r >> 2) + 4 * hi;
      float ib = __shfl(inv, qloc, 64);
      const int qrow = q0 + qloc;
      size_t base = ((size_t)(b * 2048 + qrow)) * 2048 + h * 128 + l31;
#pragma unroll
      for (int jd = 0; jd < 4; ++jd)
        y[base + 32 * jd] = f2bf(yacc[jd][r] * ib);
    }
  }
}

extern "C" void kernel_launch(void* const* d_in, const int* in_sizes, int n_in,
                              void* d_out, int out_size, void* d_ws, size_t ws_size,
                              hipStream_t stream) {
  const float* x  = (const float*)d_in[0];
  const float* Wq = (const float*)d_in[1];
  const float* Wk = (const float*)d_in[2];
  const float* Wv = (const float*)d_in[3];
  const float* Wp = (const float*)d_in[4];
  const float* qg = (const float*)d_in[5];
  float* out = (float*)d_out;

  char* ws = (char*)d_ws;
  size_t off = 0;
  auto alloc = [&](size_t bytes) {
    void* p = ws + off;
    off += (bytes + 255) & ~(size_t)255;
    return p;
  };
  u16* x_bf  = (u16*)alloc((size_t)8192 * 2048 * 2);   // also reused as y_bf
  u16* wq_bf = (u16*)alloc((size_t)2048 * 2048 * 2);   // also reused as vt_bf
  u16* wk_bf = (u16*)alloc((size_t)512 * 2048 * 2);
  u16* wv_bf = (u16*)alloc((size_t)512 * 2048 * 2);
  u16* wp_bf = (u16*)alloc((size_t)2048 * 2048 * 2);
  u16* q_bf  = (u16*)alloc((size_t)4 * 16 * 2048 * 128 * 2);
  u16* k_bf  = (u16*)alloc((size_t)4 * 4 * 2048 * 128 * 2);
  u16* v_bf  = (u16*)alloc((size_t)4 * 4 * 2048 * 128 * 2);
  float* tab = (float*)alloc((size_t)2032 * 64 * 2 * 4);
  u16* y_bf  = x_bf;    // x dead after QKV GEMM
  u16* vt_bf = wq_bf;   // Wq dead after QKV GEMM (same size)

  cvt_bf16<<<2048, 256, 0, stream>>>((const float4*)x,  (uint2*)x_bf,  8192 * 2048 / 4);
  cvt_bf16<<<512,  256, 0, stream>>>((const float4*)Wq, (uint2*)wq_bf, 2048 * 2048 / 4);
  cvt_bf16<<<128,  256, 0, stream>>>((const float4*)Wk, (uint2*)wk_bf, 512 * 2048 / 4);
  cvt_bf16<<<128,  256, 0, stream>>>((const float4*)Wv, (uint2*)wv_bf, 512 * 2048 / 4);
  cvt_bf16<<<512,  256, 0, stream>>>((const float4*)Wp, (uint2*)wp_bf, 2048 * 2048 / 4);
  rope_table<<<(2032 * 64 + 255) / 256, 256, 0, stream>>>(tab, tab + 2032 * 64);

  gemm_nt<0><<<dim3(64, 24), 256, 0, stream>>>(x_bf, wq_bf, wk_bf, wv_bf,
                                               q_bf, k_bf, v_bf, nullptr);
  norm_rope<<<2048, 256, 0, stream>>>(q_bf, 16, qg, tab, tab + 2032 * 64, 4 * 16 * 2048);
  norm_rope<<<512,  256, 0, stream>>>(k_bf, 4, nullptr, tab, tab + 2032 * 64, 4 * 4 * 2048);
  transpose_v<<<dim3(32, 2, 16), 256, 0, stream>>>(v_bf, vt_bf);
  attn<<<dim3(32, 16), 256, 0, stream>>>(q_bf, k_bf, vt_bf, y_bf);
  gemm_nt<1><<<dim3(64, 16), 256, 0, stream>>>(y_bf, wp_bf, nullptr, nullptr,
                                               nullptr, nullptr, nullptr, out);
}

// Round 3
// 400.360 us; speedup vs baseline: 2.2260x; 1.1290x over previous
//
#include <hip/hip_runtime.h>
#include <stdint.h>

// Shapes (fixed): B=4 L=2048 D=2048 H=16 KVH=4 HD=128 M=16 T=2032
typedef unsigned short u16;
typedef short s8v __attribute__((ext_vector_type(8)));   // 8 bf16 (4 VGPR) MFMA frag
typedef float f4v __attribute__((ext_vector_type(4)));   // 16x16 MFMA accum
typedef float f16v __attribute__((ext_vector_type(16))); // 32x32 MFMA accum

typedef __attribute__((address_space(1))) char gchar;
typedef __attribute__((address_space(3))) char lchar;

static __device__ __forceinline__ u16 f2bf(float f) {
  uint32_t x = __float_as_uint(f);
  x += 0x7fffu + ((x >> 16) & 1u);            // RNE
  return (u16)(x >> 16);
}
static __device__ __forceinline__ float bf2f(u16 u) {
  return __uint_as_float(((uint32_t)u) << 16);
}
// async global->LDS, 16B per lane. LDS dest must be wave-linear (base + lane*16).
static __device__ __forceinline__ void gload_lds16(const void* g, void* l) {
  __builtin_amdgcn_global_load_lds((gchar*)(uintptr_t)g,
                                   (lchar*)(uint32_t)(uintptr_t)l, 16, 0, 0);
}

// ---------------- fp32 -> bf16 convert (vectorized) ----------------
__global__ __launch_bounds__(256) void cvt_bf16(const float4* __restrict__ src,
                                                uint2* __restrict__ dst, int n4) {
  int i = blockIdx.x * 256 + threadIdx.x;
  int st = gridDim.x * 256;
  for (; i < n4; i += st) {
    float4 v = src[i];
    uint2 o;
    o.x = (uint32_t)f2bf(v.x) | ((uint32_t)f2bf(v.y) << 16);
    o.y = (uint32_t)f2bf(v.z) | ((uint32_t)f2bf(v.w) << 16);
    dst[i] = o;
  }
}

// ---------------- RoPE cos/sin table: [T=2032][64] ----------------
__global__ __launch_bounds__(256) void rope_table(float* __restrict__ tc,
                                                  float* __restrict__ ts) {
  int i = blockIdx.x * 256 + threadIdx.x;
  if (i >= 2032 * 64) return;
  int t = i >> 6, f = i & 63;
  float invf = 1.0f / powf(10000.0f, (float)f * (1.0f / 64.0f)); // accurate powf
  float ang = (float)t * invf;
  float s, c;
  sincosf(ang, &s, &c);                                           // accurate sincos
  tc[i] = c;
  ts[i] = s;
}

// ---------------- 256x256 deep-pipelined NT GEMM: C = A(MxK) @ W(NxK)^T ----------------
// 512 threads = 8 waves (2M x 4N), per-wave 128x64 output (MFMA:LDS balanced).
// BK=32, 3-deep K-tile ring buffer (96KB LDS):
//   - stage(t+2) issued right after the barrier closing tile t-1's reads -> WAR-safe
//   - vmcnt(8) (2 tiles x 4 loads in flight, never 0 in-loop) + barrier -> RAW-safe (T4)
// LDS layout: two BK=32 rows folded per 128B physical row, 3-bit XOR slot swizzle
// (pre-swizzled global source on write + swizzled ds_read) -> 2 lanes/bank (free).
// logical (r,k8) <-> physical chunk (p=r>>1, q=(k8+4*(r&1))^(p&7)); involution verified.
// MODE 0: QKV -> bf16 scattered to (B,heads,L,HD). MODE 1: proj -> fp32 out.
template <int MODE>
__global__ __launch_bounds__(512, 2) void gemm_nt(
    const u16* __restrict__ A, const u16* __restrict__ W0,
    const u16* __restrict__ W1, const u16* __restrict__ W2,
    u16* __restrict__ O0, u16* __restrict__ O1, u16* __restrict__ O2,
    float* __restrict__ OF) {
  __shared__ u16 lA[3][256 * 32];
  __shared__ u16 lB[3][256 * 32];
  const int tid = threadIdx.x;
  const int lane = tid & 63, wid = tid >> 6;
  const int wr = wid >> 2, wc = wid & 3;          // 2M x 4N waves
  const int l15 = lane & 15, l4 = lane >> 4;

  const int NB = (MODE == 0) ? 12 : 8;
  const int nwg = gridDim.x;
  const int bid = blockIdx.x;
  const int swz = (bid & 7) * (nwg >> 3) + (bid >> 3);  // XCD-chunked (nwg%8==0)
  const int bm = swz / NB, bn = swz % NB;
  const int m0 = bm * 256;

  const u16* Wt;
  int n0r;
  if constexpr (MODE == 0) {
    if (bn < 8)       { Wt = W0; n0r = bn * 256; }
    else if (bn < 10) { Wt = W1; n0r = (bn - 8) * 256; }
    else              { Wt = W2; n0r = (bn - 10) * 256; }
  } else {
    Wt = W0; n0r = bn * 256;
  }

  // chunk cidx (0..1023) -> physical (p=cidx>>3, q=cidx&7); global (r,k8) via inverse swz
  auto stage = [&](int kt, int bsel) {
    const int kb = kt * 32;
#pragma unroll
    for (int c = 0; c < 2; ++c) {
      int cidx = tid + c * 512;
      int p = cidx >> 3, q = cidx & 7;
      int qp = q ^ (p & 7);
      int r = 2 * p + (qp >> 2), k8 = qp & 3;
      gload_lds16(A + (size_t)(m0 + r) * 2048 + kb + k8 * 8, &lA[bsel][cidx * 8]);
    }
#pragma unroll
    for (int c = 0; c < 2; ++c) {
      int cidx = tid + c * 512;
      int p = cidx >> 3, q = cidx & 7;
      int qp = q ^ (p & 7);
      int r = 2 * p + (qp >> 2), k8 = qp & 3;
      gload_lds16(Wt + (size_t)(n0r + r) * 2048 + kb + k8 * 8, &lB[bsel][cidx * 8]);
    }
  };
  // swizzled ds_read offset (u16 units) for logical row fr, 16B-slot l4
  auto swzoff = [&](int fr, int s) {
    return (fr >> 1) * 64 + (((s + ((fr & 1) << 2)) ^ ((fr >> 1) & 7)) << 3);
  };

  const f4v Z4 = {0.f, 0.f, 0.f, 0.f};
  f4v acc[8][4];
#pragma unroll
  for (int i = 0; i < 8; i++)
#pragma unroll
    for (int j = 0; j < 4; j++) acc[i][j] = Z4;

  stage(0, 0);
  stage(1, 1);

  const int NT = 64;                 // 2048 / 32
  int cur = 0;
  for (int t = 0; t < NT; ++t) {
    // close previous iteration's LDS reads, then reopen the ring slot
    asm volatile("s_waitcnt lgkmcnt(0)" ::: "memory");
    __builtin_amdgcn_sched_barrier(0);
    asm volatile("s_barrier" ::: "memory");                       // B1
    const int nx2 = (cur == 0) ? 2 : cur - 1;                     // (t+2)%3
    if (t + 2 < NT) {
      stage(t + 2, nx2);
      asm volatile("s_waitcnt vmcnt(8)" ::: "memory");            // tile t landed
    } else if (t + 1 < NT) {
      asm volatile("s_waitcnt vmcnt(4)" ::: "memory");
    } else {
      asm volatile("s_waitcnt vmcnt(0)" ::: "memory");
    }
    asm volatile("s_barrier" ::: "memory");                       // B2: tile t visible

    const u16* pa = &lA[cur][0];
    const u16* pb = &lB[cur][0];
    s8v bfrg[4], afrg[4];
#pragma unroll
    for (int j = 0; j < 4; ++j)
      bfrg[j] = *(const s8v*)&pb[swzoff(wc * 64 + j * 16 + l15, l4)];
#pragma unroll
    for (int i = 0; i < 4; ++i)
      afrg[i] = *(const s8v*)&pa[swzoff(wr * 128 + i * 16 + l15, l4)];
    __builtin_amdgcn_s_setprio(1);
#pragma unroll
    for (int i = 0; i < 4; ++i)
#pragma unroll
      for (int j = 0; j < 4; ++j)
        acc[i][j] = __builtin_amdgcn_mfma_f32_16x16x32_bf16(afrg[i], bfrg[j], acc[i][j], 0, 0, 0);
    __builtin_amdgcn_s_setprio(0);
    asm volatile("s_barrier" ::: "memory");                       // B3: phase lock
#pragma unroll
    for (int i = 0; i < 4; ++i)
      afrg[i] = *(const s8v*)&pa[swzoff(wr * 128 + (i + 4) * 16 + l15, l4)];
    __builtin_amdgcn_s_setprio(1);
#pragma unroll
    for (int i = 0; i < 4; ++i)
#pragma unroll
      for (int j = 0; j < 4; ++j)
        acc[i + 4][j] = __builtin_amdgcn_mfma_f32_16x16x32_bf16(afrg[i], bfrg[j], acc[i + 4][j], 0, 0, 0);
    __builtin_amdgcn_s_setprio(0);

    cur = (cur == 2) ? 0 : cur + 1;
  }

  const int ncol0 = bn * 256 + wc * 64;           // wave's 64-col stripe (head-aligned)
  if constexpr (MODE == 0) {
    u16* Ob; int hh, HX;
    if (ncol0 < 2048)      { Ob = O0; hh = ncol0 >> 7;          HX = 16; }
    else if (ncol0 < 2560) { Ob = O1; hh = (ncol0 - 2048) >> 7; HX = 4; }
    else                   { Ob = O2; hh = (ncol0 - 2560) >> 7; HX = 4; }
    const int d0 = ncol0 & 127;
#pragma unroll
    for (int i = 0; i < 8; i++)
#pragma unroll
      for (int r = 0; r < 4; r++) {
        int m = m0 + wr * 128 + i * 16 + l4 * 4 + r;
        int b = m >> 11, l = m & 2047;
        size_t base = ((size_t)(b * HX + hh) * 2048 + l) * 128 + d0;
#pragma unroll
        for (int j = 0; j < 4; j++)
          Ob[base + j * 16 + l15] = f2bf(acc[i][j][r]);
      }
  } else {
#pragma unroll
    for (int i = 0; i < 8; i++)
#pragma unroll
      for (int r = 0; r < 4; r++) {
        int m = m0 + wr * 128 + i * 16 + l4 * 4 + r;
#pragma unroll
        for (int j = 0; j < 4; j++)
          OF[(size_t)m * 2048 + ncol0 + j * 16 + l15] = acc[i][j][r];
      }
  }
}

// ---------------- RMSNorm + RoPE + gain, in place, one wave per 128-wide row
__global__ __launch_bounds__(256) void norm_rope(u16* __restrict__ buf, int nh,
                                                 const float* __restrict__ gain,
                                                 const float* __restrict__ tc,
                                                 const float* __restrict__ ts,
                                                 int nrows) {
  const int lane = threadIdx.x & 63;
  const int gw = blockIdx.x * 4 + (threadIdx.x >> 6);
  const int nw = gridDim.x * 4;
  for (int row = gw; row < nrows; row += nw) {
    int l = row & 2047;
    int h = (row >> 11) % nh;
    u16* p = buf + (size_t)row * 128;
    float x1 = bf2f(p[lane]);
    float x2 = bf2f(p[lane + 64]);
    float ss = x1 * x1 + x2 * x2;
#pragma unroll
    for (int off = 32; off > 0; off >>= 1) ss += __shfl_xor(ss, off, 64);
    float r = rsqrtf(ss * (1.0f / 128.0f) + 1.1920929e-07f);
    x1 *= r; x2 *= r;
    if (l >= 16) {
      int t = l - 16;
      float c = tc[t * 64 + lane], s = ts[t * 64 + lane];
      float o1 = x1 * c + x2 * s;
      float o2 = -x1 * s + x2 * c;
      x1 = o1; x2 = o2;
    }
    if (gain) { float g = gain[h]; x1 *= g; x2 *= g; }
    p[lane] = f2bf(x1);
    p[lane + 64] = f2bf(x2);
  }
}

// ---------------- V transpose: (bg,L,128) -> (bg,128,L), 64x64 LDS tiles, XOR swizzle
__global__ __launch_bounds__(256) void transpose_v(const u16* __restrict__ v,
                                                   u16* __restrict__ vt) {
  __shared__ u16 t[64][64];
  const int l0 = blockIdx.x * 64, d0 = blockIdx.y * 64, bg = blockIdx.z;
  const int tid = threadIdx.x;
#pragma unroll
  for (int it = 0; it < 2; ++it) {
    int lin = it * 256 + tid;
    int r = lin >> 3, cb = lin & 7;
    s8v val = *(const s8v*)&v[((bg * 2048 + l0 + r) * 128) + d0 + cb * 8];
    *(s8v*)&t[r][(cb ^ (r & 7)) * 8] = val;
  }
  __syncthreads();
#pragma unroll
  for (int it = 0; it < 2; ++it) {
    int lin = it * 256 + tid;
    int r2 = lin >> 3, c2 = (lin & 7) * 8;   // r2 = d idx, c2 = l idx
    s8v o;
#pragma unroll
    for (int j = 0; j < 8; ++j) {
      int rr = c2 + j, cc = r2;
      o[j] = (short)t[rr][(cc & 7) + 8 * ((cc >> 3) ^ (rr & 7))];
    }
    *(s8v*)&vt[((bg * 128 + d0 + r2) * 2048) + l0 + c2] = o;
  }
}

// ---------------- flash attention, 32x32 swapped-QK^T structure ----------------
// block = 4 waves = 4 q-heads of one KV group, 32 q-rows each; KVBLK=64.
// Causal pairing: block i handles q-tiles {i, 63-i} -> uniform 33-34 KV iters.
// Swapped QK^T (mfma(K,Q) -> C[kv][q]): lane owns q-row (lane&31); softmax fully
// in-register; P->PV A-frag rebuilt via bf16 pack + shfl_xor(32); defer-max THR=8.
__global__ __launch_bounds__(256, 2) void attn(const u16* __restrict__ q,
                                               const u16* __restrict__ k,
                                               const u16* __restrict__ vt,
                                               u16* __restrict__ y) {
  __shared__ u16 lK[2][64 * 128];   // row kv: 16 slots of 8 u16, slot s holds d-block s^(kv&7)
  __shared__ u16 lVT[2][128 * 64];  // row d:   8 slots of 8 u16, slot s holds kv-block s^(d&7)
  const int tid = threadIdx.x;
  const int lane = tid & 63, wid = tid >> 6;
  const int l31 = lane & 31, hi = lane >> 5;

  // XCD-aware remap: all 32 pair-blocks of one (b,g) land on one XCD (KV panel in L2)
  const int db = (int)blockIdx.y * 32 + (int)blockIdx.x;  // 0..511
  const int half = db >> 8, rem = db & 255;
  const int bg = (rem & 7) + 8 * half;                    // 0..15
  const int pairi = rem >> 3;                             // 0..31
  const int b = bg >> 2, g = bg & 3;
  const int h = g * 4 + wid;

  const u16* qh = q + (size_t)(b * 16 + h) * 2048 * 128;
  const u16* kb0 = k + (size_t)(b * 4 + g) * 2048 * 128;
  const u16* vtb0 = vt + (size_t)(b * 4 + g) * 128 * 2048;
  const float scale = 0.08838834764831845f;  // 1/sqrt(128)

  auto stage = [&](int t, int bufsel) {
    const int kv0 = t * 64;
#pragma unroll
    for (int it = 0; it < 4; ++it) {        // K tile 64x128 (16KB), swizzled source
      int lin = it * 256 + tid;
      int kj = lin >> 4, s = lin & 15;
      gload_lds16(kb0 + (size_t)(kv0 + kj) * 128 + ((s ^ (kj & 7)) * 8),
                  &lK[bufsel][lin * 8]);
    }
#pragma unroll
    for (int it = 0; it < 4; ++it) {        // VT tile 128x64 (16KB), swizzled source
      int lin = it * 256 + tid;
      int d = lin >> 3, s = lin & 7;
      gload_lds16(vtb0 + (size_t)d * 2048 + kv0 + ((s ^ (d & 7)) * 8),
                  &lVT[bufsel][lin * 8]);
    }
  };

  for (int ph = 0; ph < 2; ++ph) {
    const int qt = ph ? (63 - pairi) : pairi;
    const int q0 = qt * 32;
    const int nt = (q0 >> 6) + 1;           // KV tiles of 64 covering [0, q0+32)
    const int qabs = q0 + l31;

    // Q fragments: B-operand, col=q (lane&31), k = d = ks*16 + 8*hi + jj
    s8v qf[8];
#pragma unroll
    for (int ks = 0; ks < 8; ++ks)
      qf[ks] = *(const s8v*)&qh[(q0 + l31) * 128 + ks * 16 + hi * 8];

    f16v yacc[4];
#pragma unroll
    for (int j = 0; j < 4; ++j)
#pragma unroll
      for (int r = 0; r < 16; ++r) yacc[j][r] = 0.f;
    float mrow = -1e30f, lrow = 0.f;

    stage(0, 0);
    __syncthreads();

    for (int t = 0; t < nt; ++t) {
      const int cur = t & 1;
      if (t + 1 < nt) stage(t + 1, cur ^ 1);
      const int kv0 = t * 64;

      // ---- QK^T swapped: S^T[kv][q], two 32-kv chunks ----
      f16v s0a, s1a;
#pragma unroll
      for (int r = 0; r < 16; ++r) { s0a[r] = 0.f; s1a[r] = 0.f; }
#pragma unroll
      for (int ks = 0; ks < 8; ++ks) {
        const int slot = (2 * ks + hi) ^ (l31 & 7);
        s8v kf0 = *(const s8v*)&lK[cur][(l31)*128 + slot * 8];
        s8v kf1 = *(const s8v*)&lK[cur][(32 + l31) * 128 + slot * 8];
        s0a = __builtin_amdgcn_mfma_f32_32x32x16_bf16(kf0, qf[ks], s0a, 0, 0, 0);
        s1a = __builtin_amdgcn_mfma_f32_32x32x16_bf16(kf1, qf[ks], s1a, 0, 0, 0);
      }

      // ---- scale + causal mask + row max (in-register) ----
      const bool last = (t == nt - 1);
      float p0[16], p1[16];
      float pmax = -1e30f;
#pragma unroll
      for (int r = 0; r < 16; ++r) {
        const int kvloc = (r & 3) + 8 * (r >> 2) + 4 * hi;
        float v0 = s0a[r] * scale;
        float v1 = s1a[r] * scale;
        if (last) {
          if (kv0 + kvloc > qabs) v0 = -1e30f;
          if (kv0 + 32 + kvloc > qabs) v1 = -1e30f;
        }
        p0[r] = v0; p1[r] = v1;
        pmax = fmaxf(pmax, fmaxf(v0, v1));
      }
      pmax = fmaxf(pmax, __shfl_xor(pmax, 32, 64));

      // ---- defer-max (T13): rescale only when max grows past THR=8 ----
      if (!__all(pmax - mrow <= 8.0f)) {
        float mnew = fmaxf(mrow, pmax);
        float corr = __expf(mrow - mnew);
#pragma unroll
        for (int r = 0; r < 16; ++r) {
          const int qloc = (r & 3) + 8 * (r >> 2) + 4 * hi;
          float cb = __shfl(corr, qloc, 64);
          yacc[0][r] *= cb; yacc[1][r] *= cb; yacc[2][r] *= cb; yacc[3][r] *= cb;
        }
        lrow *= corr;
        mrow = mnew;
      }

      // ---- exp (bf16-rounded so denom matches MFMA numerator) + row sum ----
      float ps = 0.f;
#pragma unroll
      for (int r = 0; r < 16; ++r) {
        float e0 = bf2f(f2bf(__expf(p0[r] - mrow)));
        float e1 = bf2f(f2bf(__expf(p1[r] - mrow)));
        p0[r] = e0; p1[r] = e1;
        ps += e0 + e1;
      }
      ps += __shfl_xor(ps, 32, 64);
      lrow += ps;

      // ---- PV: rebuild A-frag (P rows = q) via pack + half-wave exchange ----
#pragma unroll
      for (int ks = 0; ks < 4; ++ks) {
        const float* pc = (ks < 2) ? p0 : p1;
        const int rb = 8 * (ks & 1);
        uint32_t A0 = (uint32_t)f2bf(pc[rb + 0]) | ((uint32_t)f2bf(pc[rb + 1]) << 16);
        uint32_t A1 = (uint32_t)f2bf(pc[rb + 2]) | ((uint32_t)f2bf(pc[rb + 3]) << 16);
        uint32_t B0 = (uint32_t)f2bf(pc[rb + 4]) | ((uint32_t)f2bf(pc[rb + 5]) << 16);
        uint32_t B1 = (uint32_t)f2bf(pc[rb + 6]) | ((uint32_t)f2bf(pc[rb + 7]) << 16);
        uint32_t t0 = hi ? A0 : B0;
        uint32_t t1 = hi ? A1 : B1;
        uint32_t r0 = (uint32_t)__shfl_xor((int)t0, 32, 64);
        uint32_t r1 = (uint32_t)__shfl_xor((int)t1, 32, 64);
        union { uint32_t u[4]; s8v v; } uu;
        uu.u[0] = hi ? r0 : A0;
        uu.u[1] = hi ? r1 : A1;
        uu.u[2] = hi ? B0 : r0;
        uu.u[3] = hi ? B1 : r1;
#pragma unroll
        for (int jd = 0; jd < 4; ++jd) {
          const int rowd = 32 * jd + l31;
          const int slot = (2 * ks + hi) ^ (l31 & 7);
          s8v vf = *(const s8v*)&lVT[cur][rowd * 64 + slot * 8];
          yacc[jd] = __builtin_amdgcn_mfma_f32_32x32x16_bf16(uu.v, vf, yacc[jd], 0, 0, 0);
        }
      }
      __syncthreads();
    }

    // ---- finalize: broadcast 1/l per C-row, write y (B,L,H*128) bf16 ----
    float inv = 1.0f / lrow;
#pragma unroll
    for (int r = 0; r < 16; ++r) {
      const int qloc = (r & 3) + 8 * (r >> 2) + 4 * hi;
      float ib = __shfl(inv, qloc, 64);
      const int qrow = q0 + qloc;
      size_t base = ((size_t)(b * 2048 + qrow)) * 2048 + h * 128 + l31;
#pragma unroll
      for (int jd = 0; jd < 4; ++jd)
        y[base + 32 * jd] = f2bf(yacc[jd][r] * ib);
    }
  }
}

extern "C" void kernel_launch(void* const* d_in, const int* in_sizes, int n_in,
                              void* d_out, int out_size, void* d_ws, size_t ws_size,
                              hipStream_t stream) {
  const float* x  = (const float*)d_in[0];
  const float* Wq = (const float*)d_in[1];
  const float* Wk = (const float*)d_in[2];
  const float* Wv = (const float*)d_in[3];
  const float* Wp = (const float*)d_in[4];
  const float* qg = (const float*)d_in[5];
  float* out = (float*)d_out;

  char* ws = (char*)d_ws;
  size_t off = 0;
  auto alloc = [&](size_t bytes) {
    void* p = ws + off;
    off += (bytes + 255) & ~(size_t)255;
    return p;
  };
  u16* x_bf  = (u16*)alloc((size_t)8192 * 2048 * 2);   // also reused as y_bf
  u16* wq_bf = (u16*)alloc((size_t)2048 * 2048 * 2);   // also reused as vt_bf
  u16* wk_bf = (u16*)alloc((size_t)512 * 2048 * 2);
  u16* wv_bf = (u16*)alloc((size_t)512 * 2048 * 2);
  u16* wp_bf = (u16*)alloc((size_t)2048 * 2048 * 2);
  u16* q_bf  = (u16*)alloc((size_t)4 * 16 * 2048 * 128 * 2);
  u16* k_bf  = (u16*)alloc((size_t)4 * 4 * 2048 * 128 * 2);
  u16* v_bf  = (u16*)alloc((size_t)4 * 4 * 2048 * 128 * 2);
  float* tab = (float*)alloc((size_t)2032 * 64 * 2 * 4);
  u16* y_bf  = x_bf;    // x dead after QKV GEMM
  u16* vt_bf = wq_bf;   // Wq dead after QKV GEMM (same size)

  cvt_bf16<<<2048, 256, 0, stream>>>((const float4*)x,  (uint2*)x_bf,  8192 * 2048 / 4);
  cvt_bf16<<<512,  256, 0, stream>>>((const float4*)Wq, (uint2*)wq_bf, 2048 * 2048 / 4);
  cvt_bf16<<<128,  256, 0, stream>>>((const float4*)Wk, (uint2*)wk_bf, 512 * 2048 / 4);
  cvt_bf16<<<128,  256, 0, stream>>>((const float4*)Wv, (uint2*)wv_bf, 512 * 2048 / 4);
  cvt_bf16<<<512,  256, 0, stream>>>((const float4*)Wp, (uint2*)wp_bf, 2048 * 2048 / 4);
  rope_table<<<(2032 * 64 + 255) / 256, 256, 0, stream>>>(tab, tab + 2032 * 64);

  gemm_nt<0><<<dim3(384), 512, 0, stream>>>(x_bf, wq_bf, wk_bf, wv_bf,
                                            q_bf, k_bf, v_bf, nullptr);
  norm_rope<<<2048, 256, 0, stream>>>(q_bf, 16, qg, tab, tab + 2032 * 64, 4 * 16 * 2048);
  norm_rope<<<512,  256, 0, stream>>>(k_bf, 4, nullptr, tab, tab + 2032 * 64, 4 * 4 * 2048);
  transpose_v<<<dim3(32, 2, 16), 256, 0, stream>>>(v_bf, vt_bf);
  attn<<<dim3(32, 16), 256, 0, stream>>>(q_bf, k_bf, vt_bf, y_bf);
  gemm_nt<1><<<dim3(256), 512, 0, stream>>>(y_bf, wp_bf, nullptr, nullptr,
                                            nullptr, nullptr, nullptr, out);
}

// Round 5
// 376.267 us; speedup vs baseline: 2.3686x; 1.0640x over previous
//
#include <hip/hip_runtime.h>
#include <stdint.h>

// Shapes (fixed): B=4 L=2048 D=2048 H=16 KVH=4 HD=128 M=16 T=2032
typedef unsigned short u16;
typedef short s8v __attribute__((ext_vector_type(8)));   // 8 bf16 (4 VGPR) MFMA frag
typedef float f4v __attribute__((ext_vector_type(4)));   // 16x16 MFMA accum
typedef float f16v __attribute__((ext_vector_type(16))); // 32x32 MFMA accum

typedef __attribute__((address_space(1))) char gchar;
typedef __attribute__((address_space(3))) char lchar;

static __device__ __forceinline__ u16 f2bf(float f) {
  uint32_t x = __float_as_uint(f);
  x += 0x7fffu + ((x >> 16) & 1u);            // RNE
  return (u16)(x >> 16);
}
static __device__ __forceinline__ float bf2f(u16 u) {
  return __uint_as_float(((uint32_t)u) << 16);
}
// async global->LDS, 16B per lane. LDS dest must be wave-linear (base + lane*16).
static __device__ __forceinline__ void gload_lds16(const void* g, void* l) {
  __builtin_amdgcn_global_load_lds((gchar*)(uintptr_t)g,
                                   (lchar*)(uint32_t)(uintptr_t)l, 16, 0, 0);
}

// ---------------- fp32 -> bf16 convert (vectorized) ----------------
__global__ __launch_bounds__(256) void cvt_bf16(const float4* __restrict__ src,
                                                uint2* __restrict__ dst, int n4) {
  int i = blockIdx.x * 256 + threadIdx.x;
  int st = gridDim.x * 256;
  for (; i < n4; i += st) {
    float4 v = src[i];
    uint2 o;
    o.x = (uint32_t)f2bf(v.x) | ((uint32_t)f2bf(v.y) << 16);
    o.y = (uint32_t)f2bf(v.z) | ((uint32_t)f2bf(v.w) << 16);
    dst[i] = o;
  }
}

// all 4 weight matrices in one launch; dst regions are contiguous in ws.
__global__ __launch_bounds__(256) void cvt_bf16_w(const float4* __restrict__ s0,
                                                  const float4* __restrict__ s1,
                                                  const float4* __restrict__ s2,
                                                  const float4* __restrict__ s3,
                                                  uint2* __restrict__ dst) {
  // boundaries in float4 units: wq 1048576 | wk 262144 | wv 262144 | wp 1048576
  int i = blockIdx.x * 256 + threadIdx.x;
  int st = gridDim.x * 256;
  for (; i < 2621440; i += st) {
    const float4* s;
    int off;
    if (i < 1048576)      { s = s0; off = i; }
    else if (i < 1310720) { s = s1; off = i - 1048576; }
    else if (i < 1572864) { s = s2; off = i - 1310720; }
    else                  { s = s3; off = i - 1572864; }
    float4 v = s[off];
    uint2 o;
    o.x = (uint32_t)f2bf(v.x) | ((uint32_t)f2bf(v.y) << 16);
    o.y = (uint32_t)f2bf(v.z) | ((uint32_t)f2bf(v.w) << 16);
    dst[i] = o;
  }
}

// ---------------- RoPE cos/sin table: [T=2032][64] ----------------
__global__ __launch_bounds__(256) void rope_table(float* __restrict__ tc,
                                                  float* __restrict__ ts) {
  int i = blockIdx.x * 256 + threadIdx.x;
  if (i >= 2032 * 64) return;
  int t = i >> 6, f = i & 63;
  float invf = 1.0f / powf(10000.0f, (float)f * (1.0f / 64.0f)); // accurate powf
  float ang = (float)t * invf;
  float s, c;
  sincosf(ang, &s, &c);                                           // accurate sincos
  tc[i] = c;
  ts[i] = s;
}

// ---------------- 256x128 deep-ring NT GEMM: C = A(MxK) @ W(NxK)^T ----------------
// 512 threads = 8 waves (4M x 2N), per-wave 64x64 output -> LDS:MFMA balanced
// (per CU per K=32: 64KB LDS reads ~512cy vs ~516cy MFMA; A re-read only 2x).
// BK=32, 4-slot ring (96KB LDS), TWO barriers per iteration (RAW barrier is
// mandatory: vmcnt(N) only drains the issuing wave's own load queue — reads
// consume chunks staged by OTHER waves, so all waves must certify their tile-t
// loads landed BEFORE anyone ds_reads; this was R4's race):
//   top: lgkmcnt(0)+sched_barrier+s_barrier  (closes iter t-1 reads -> WAR-safe)
//   stage(t+3) into slot (t+3)&3 (freed at iter t-1)
//   s_waitcnt vmcnt(9) = own tile-t loads landed (counted, T4; never 0 in-loop)
//   s_barrier                                 (ALL waves' tile-t loads landed -> RAW)
//   8x ds_read_b128 (fold+XOR swizzle, conflict-free) + setprio'd 16 MFMA (T5)
// Grids are even multiples of 256 CUs: mode0 768, mode1 512 -> no tail rounds.
// MODE 0: QKV -> bf16 scattered to (B,heads,L,HD). MODE 1: proj -> fp32 out.
template <int MODE>
__global__ __launch_bounds__(512, 2) void gemm_nt(
    const u16* __restrict__ A, const u16* __restrict__ W0,
    const u16* __restrict__ W1, const u16* __restrict__ W2,
    u16* __restrict__ O0, u16* __restrict__ O1, u16* __restrict__ O2,
    float* __restrict__ OF) {
  __shared__ u16 lA[4][256 * 32];
  __shared__ u16 lB[4][128 * 32];
  const int tid = threadIdx.x;
  const int lane = tid & 63, wid = tid >> 6;
  const int wr = wid >> 1, wc = wid & 1;          // 4M x 2N waves
  const int l15 = lane & 15, l4 = lane >> 4;

  const int NB = (MODE == 0) ? 24 : 16;
  const int nwg = gridDim.x;
  const int bid = blockIdx.x;
  const int swz = (bid & 7) * (nwg >> 3) + (bid >> 3);  // XCD-chunked (nwg%8==0)
  const int bm = swz / NB, bn = swz % NB;
  const int m0 = bm * 256;

  const u16* Wt;
  int n0r;
  if constexpr (MODE == 0) {
    if (bn < 16)      { Wt = W0; n0r = bn * 128; }
    else if (bn < 20) { Wt = W1; n0r = (bn - 16) * 128; }
    else              { Wt = W2; n0r = (bn - 20) * 128; }
  } else {
    Wt = W0; n0r = bn * 128;
  }

  // chunk cidx -> physical (p=cidx>>3, q=cidx&7); global (r,k8) via inverse swz
  auto stage = [&](int kt, int bsel) {
    const int kb = kt * 32;
#pragma unroll
    for (int c = 0; c < 2; ++c) {                 // A: 256x32 = 1024 chunks
      int cidx = tid + c * 512;
      int p = cidx >> 3, q = cidx & 7;
      int qp = q ^ (p & 7);
      int r = 2 * p + (qp >> 2), k8 = qp & 3;
      gload_lds16(A + (size_t)(m0 + r) * 2048 + kb + k8 * 8, &lA[bsel][cidx * 8]);
    }
    {                                             // B: 128x32 = 512 chunks
      int cidx = tid;
      int p = cidx >> 3, q = cidx & 7;
      int qp = q ^ (p & 7);
      int r = 2 * p + (qp >> 2), k8 = qp & 3;
      gload_lds16(Wt + (size_t)(n0r + r) * 2048 + kb + k8 * 8, &lB[bsel][cidx * 8]);
    }
  };
  // swizzled ds_read offset (u16 units) for logical row fr, 16B-slot s (0..3)
  auto swzoff = [&](int fr, int s) {
    return (fr >> 1) * 64 + (((s + ((fr & 1) << 2)) ^ ((fr >> 1) & 7)) << 3);
  };

  const f4v Z4 = {0.f, 0.f, 0.f, 0.f};
  f4v acc[4][4];
#pragma unroll
  for (int i = 0; i < 4; i++)
#pragma unroll
    for (int j = 0; j < 4; j++) acc[i][j] = Z4;

  stage(0, 0);
  stage(1, 1);
  stage(2, 2);

  const int NT = 64;                 // 2048 / 32
  for (int t = 0; t < NT; ++t) {
    const int cur = t & 3;
    asm volatile("s_waitcnt lgkmcnt(0)" ::: "memory");
    __builtin_amdgcn_sched_barrier(0);
    asm volatile("s_barrier" ::: "memory");       // WAR: iter t-1 reads closed
    if (t + 3 < NT) {
      stage(t + 3, (t + 3) & 3);
      asm volatile("s_waitcnt vmcnt(9)" ::: "memory");   // own tile-t loads landed
    } else if (t == NT - 3) {
      asm volatile("s_waitcnt vmcnt(6)" ::: "memory");
    } else if (t == NT - 2) {
      asm volatile("s_waitcnt vmcnt(3)" ::: "memory");
    } else {
      asm volatile("s_waitcnt vmcnt(0)" ::: "memory");
    }
    asm volatile("s_barrier" ::: "memory");       // RAW: ALL waves' tile t landed

    const u16* pa = &lA[cur][0];
    const u16* pb = &lB[cur][0];
    s8v afrg[4], bfrg[4];
#pragma unroll
    for (int i = 0; i < 4; ++i)
      afrg[i] = *(const s8v*)&pa[swzoff(wr * 64 + i * 16 + l15, l4)];
#pragma unroll
    for (int j = 0; j < 4; ++j)
      bfrg[j] = *(const s8v*)&pb[swzoff(wc * 64 + j * 16 + l15, l4)];
    __builtin_amdgcn_s_setprio(1);
#pragma unroll
    for (int i = 0; i < 4; ++i)
#pragma unroll
      for (int j = 0; j < 4; ++j)
        acc[i][j] = __builtin_amdgcn_mfma_f32_16x16x32_bf16(afrg[i], bfrg[j], acc[i][j], 0, 0, 0);
    __builtin_amdgcn_s_setprio(0);
  }

  const int ncol0 = bn * 128 + wc * 64;           // 64-col stripe (head-half aligned)
  if constexpr (MODE == 0) {
    const int colg = ncol0;                       // within 3072 = Q|K|V
    u16* Ob; int hh, HX;
    if (colg < 2048)      { Ob = O0; hh = colg >> 7;          HX = 16; }
    else if (colg < 2560) { Ob = O1; hh = (colg - 2048) >> 7; HX = 4; }
    else                  { Ob = O2; hh = (colg - 2560) >> 7; HX = 4; }
    const int d0 = colg & 127;
#pragma unroll
    for (int i = 0; i < 4; i++)
#pragma unroll
      for (int r = 0; r < 4; r++) {
        int m = m0 + wr * 64 + i * 16 + l4 * 4 + r;
        int b = m >> 11, l = m & 2047;
        size_t base = ((size_t)(b * HX + hh) * 2048 + l) * 128 + d0;
#pragma unroll
        for (int j = 0; j < 4; j++)
          Ob[base + j * 16 + l15] = f2bf(acc[i][j][r]);
      }
  } else {
#pragma unroll
    for (int i = 0; i < 4; i++)
#pragma unroll
      for (int r = 0; r < 4; r++) {
        int m = m0 + wr * 64 + i * 16 + l4 * 4 + r;
#pragma unroll
        for (int j = 0; j < 4; j++)
          OF[(size_t)m * 2048 + ncol0 + j * 16 + l15] = acc[i][j][r];
      }
  }
}

// ---------------- RMSNorm + RoPE + gain, in place, one wave per 128-wide row
// q rows [0,131072) then k rows [131072,163840) — q_bf/k_bf contiguous in ws.
__global__ __launch_bounds__(256) void norm_rope(u16* __restrict__ buf,
                                                 const float* __restrict__ gain,
                                                 const float* __restrict__ tc,
                                                 const float* __restrict__ ts) {
  const int lane = threadIdx.x & 63;
  const int gw = blockIdx.x * 4 + (threadIdx.x >> 6);
  const int nw = gridDim.x * 4;
  for (int row = gw; row < 163840; row += nw) {
    int l = row & 2047;
    u16* p = buf + (size_t)row * 128;
    float x1 = bf2f(p[lane]);
    float x2 = bf2f(p[lane + 64]);
    float ss = x1 * x1 + x2 * x2;
#pragma unroll
    for (int off = 32; off > 0; off >>= 1) ss += __shfl_xor(ss, off, 64);
    float r = rsqrtf(ss * (1.0f / 128.0f) + 1.1920929e-07f);
    x1 *= r; x2 *= r;
    if (l >= 16) {
      int t = l - 16;
      float c = tc[t * 64 + lane], s = ts[t * 64 + lane];
      float o1 = x1 * c + x2 * s;
      float o2 = -x1 * s + x2 * c;
      x1 = o1; x2 = o2;
    }
    if (row < 131072) {            // q: apply per-head gain
      float g = gain[(row >> 11) & 15];
      x1 *= g; x2 *= g;
    }
    p[lane] = f2bf(x1);
    p[lane + 64] = f2bf(x2);
  }
}

// ---------------- V transpose: (bg,L,128) -> (bg,128,L), 64x64 LDS tiles, XOR swizzle
__global__ __launch_bounds__(256) void transpose_v(const u16* __restrict__ v,
                                                   u16* __restrict__ vt) {
  __shared__ u16 t[64][64];
  const int l0 = blockIdx.x * 64, d0 = blockIdx.y * 64, bg = blockIdx.z;
  const int tid = threadIdx.x;
#pragma unroll
  for (int it = 0; it < 2; ++it) {
    int lin = it * 256 + tid;
    int r = lin >> 3, cb = lin & 7;
    s8v val = *(const s8v*)&v[((bg * 2048 + l0 + r) * 128) + d0 + cb * 8];
    *(s8v*)&t[r][(cb ^ (r & 7)) * 8] = val;
  }
  __syncthreads();
#pragma unroll
  for (int it = 0; it < 2; ++it) {
    int lin = it * 256 + tid;
    int r2 = lin >> 3, c2 = (lin & 7) * 8;   // r2 = d idx, c2 = l idx
    s8v o;
#pragma unroll
    for (int j = 0; j < 8; ++j) {
      int rr = c2 + j, cc = r2;
      o[j] = (short)t[rr][(cc & 7) + 8 * ((cc >> 3) ^ (rr & 7))];
    }
    *(s8v*)&vt[((bg * 128 + d0 + r2) * 2048) + l0 + c2] = o;
  }
}

// ---------------- flash attention, 32x32 swapped-QK^T structure ----------------
// block = 4 waves = 4 q-heads of one KV group, 32 q-rows each; KVBLK=64.
// Causal pairing: block i handles q-tiles {i, 63-i} -> uniform 33-34 KV iters.
// Swapped QK^T (mfma(K,Q) -> C[kv][q]): lane owns q-row (lane&31); softmax fully
// in-register; P->PV A-frag rebuilt via bf16 pack + shfl_xor(32); defer-max THR=8.
__global__ __launch_bounds__(256, 2) void attn(const u16* __restrict__ q,
                                               const u16* __restrict__ k,
                                               const u16* __restrict__ vt,
                                               u16* __restrict__ y) {
  __shared__ u16 lK[2][64 * 128];   // row kv: 16 slots of 8 u16, slot s holds d-block s^(kv&7)
  __shared__ u16 lVT[2][128 * 64];  // row d:   8 slots of 8 u16, slot s holds kv-block s^(d&7)
  const int tid = threadIdx.x;
  const int lane = tid & 63, wid = tid >> 6;
  const int l31 = lane & 31, hi = lane >> 5;

  // XCD-aware remap: all 32 pair-blocks of one (b,g) land on one XCD (KV panel in L2)
  const int db = (int)blockIdx.y * 32 + (int)blockIdx.x;  // 0..511
  const int half = db >> 8, rem = db & 255;
  const int bg = (rem & 7) + 8 * half;                    // 0..15
  const int pairi = rem >> 3;                             // 0..31
  const int b = bg >> 2, g = bg & 3;
  const int h = g * 4 + wid;

  const u16* qh = q + (size_t)(b * 16 + h) * 2048 * 128;
  const u16* kb0 = k + (size_t)(b * 4 + g) * 2048 * 128;
  const u16* vtb0 = vt + (size_t)(b * 4 + g) * 128 * 2048;
  const float scale = 0.08838834764831845f;  // 1/sqrt(128)

  auto stage = [&](int t, int bufsel) {
    const int kv0 = t * 64;
#pragma unroll
    for (int it = 0; it < 4; ++it) {        // K tile 64x128 (16KB), swizzled source
      int lin = it * 256 + tid;
      int kj = lin >> 4, s = lin & 15;
      gload_lds16(kb0 + (size_t)(kv0 + kj) * 128 + ((s ^ (kj & 7)) * 8),
                  &lK[bufsel][lin * 8]);
    }
#pragma unroll
    for (int it = 0; it < 4; ++it) {        // VT tile 128x64 (16KB), swizzled source
      int lin = it * 256 + tid;
      int d = lin >> 3, s = lin & 7;
      gload_lds16(vtb0 + (size_t)d * 2048 + kv0 + ((s ^ (d & 7)) * 8),
                  &lVT[bufsel][lin * 8]);
    }
  };

  for (int ph = 0; ph < 2; ++ph) {
    const int qt = ph ? (63 - pairi) : pairi;
    const int q0 = qt * 32;
    const int nt = (q0 >> 6) + 1;           // KV tiles of 64 covering [0, q0+32)
    const int qabs = q0 + l31;

    // Q fragments: B-operand, col=q (lane&31), k = d = ks*16 + 8*hi + jj
    s8v qf[8];
#pragma unroll
    for (int ks = 0; ks < 8; ++ks)
      qf[ks] = *(const s8v*)&qh[(q0 + l31) * 128 + ks * 16 + hi * 8];

    f16v yacc[4];
#pragma unroll
    for (int j = 0; j < 4; ++j)
#pragma unroll
      for (int r = 0; r < 16; ++r) yacc[j][r] = 0.f;
    float mrow = -1e30f, lrow = 0.f;

    stage(0, 0);
    __syncthreads();

    for (int t = 0; t < nt; ++t) {
      const int cur = t & 1;
      if (t + 1 < nt) stage(t + 1, cur ^ 1);
      const int kv0 = t * 64;

      // ---- QK^T swapped: S^T[kv][q], two 32-kv chunks ----
      f16v s0a, s1a;
#pragma unroll
      for (int r = 0; r < 16; ++r) { s0a[r] = 0.f; s1a[r] = 0.f; }
      __builtin_amdgcn_s_setprio(1);
#pragma unroll
      for (int ks = 0; ks < 8; ++ks) {
        const int slot = (2 * ks + hi) ^ (l31 & 7);
        s8v kf0 = *(const s8v*)&lK[cur][(l31)*128 + slot * 8];
        s8v kf1 = *(const s8v*)&lK[cur][(32 + l31) * 128 + slot * 8];
        s0a = __builtin_amdgcn_mfma_f32_32x32x16_bf16(kf0, qf[ks], s0a, 0, 0, 0);
        s1a = __builtin_amdgcn_mfma_f32_32x32x16_bf16(kf1, qf[ks], s1a, 0, 0, 0);
      }
      __builtin_amdgcn_s_setprio(0);

      // ---- scale + causal mask + row max (in-register) ----
      const bool last = (t == nt - 1);
      float p0[16], p1[16];
      float pmax = -1e30f;
#pragma unroll
      for (int r = 0; r < 16; ++r) {
        const int kvloc = (r & 3) + 8 * (r >> 2) + 4 * hi;
        float v0 = s0a[r] * scale;
        float v1 = s1a[r] * scale;
        if (last) {
          if (kv0 + kvloc > qabs) v0 = -1e30f;
          if (kv0 + 32 + kvloc > qabs) v1 = -1e30f;
        }
        p0[r] = v0; p1[r] = v1;
        pmax = fmaxf(pmax, fmaxf(v0, v1));
      }
      pmax = fmaxf(pmax, __shfl_xor(pmax, 32, 64));

      // ---- defer-max (T13): rescale only when max grows past THR=8 ----
      if (!__all(pmax - mrow <= 8.0f)) {
        float mnew = fmaxf(mrow, pmax);
        float corr = __expf(mrow - mnew);
#pragma unroll
        for (int r = 0; r < 16; ++r) {
          const int qloc = (r & 3) + 8 * (r >> 2) + 4 * hi;
          float cb = __shfl(corr, qloc, 64);
          yacc[0][r] *= cb; yacc[1][r] *= cb; yacc[2][r] *= cb; yacc[3][r] *= cb;
        }
        lrow *= corr;
        mrow = mnew;
      }

      // ---- exp (bf16-rounded so denom matches MFMA numerator) + row sum ----
      float ps = 0.f;
#pragma unroll
      for (int r = 0; r < 16; ++r) {
        float e0 = bf2f(f2bf(__expf(p0[r] - mrow)));
        float e1 = bf2f(f2bf(__expf(p1[r] - mrow)));
        p0[r] = e0; p1[r] = e1;
        ps += e0 + e1;
      }
      ps += __shfl_xor(ps, 32, 64);
      lrow += ps;

      // ---- PV: rebuild A-frag (P rows = q) via pack + half-wave exchange ----
      __builtin_amdgcn_s_setprio(1);
#pragma unroll
      for (int ks = 0; ks < 4; ++ks) {
        const float* pc = (ks < 2) ? p0 : p1;
        const int rb = 8 * (ks & 1);
        uint32_t A0 = (uint32_t)f2bf(pc[rb + 0]) | ((uint32_t)f2bf(pc[rb + 1]) << 16);
        uint32_t A1 = (uint32_t)f2bf(pc[rb + 2]) | ((uint32_t)f2bf(pc[rb + 3]) << 16);
        uint32_t B0 = (uint32_t)f2bf(pc[rb + 4]) | ((uint32_t)f2bf(pc[rb + 5]) << 16);
        uint32_t B1 = (uint32_t)f2bf(pc[rb + 6]) | ((uint32_t)f2bf(pc[rb + 7]) << 16);
        uint32_t t0 = hi ? A0 : B0;
        uint32_t t1 = hi ? A1 : B1;
        uint32_t r0 = (uint32_t)__shfl_xor((int)t0, 32, 64);
        uint32_t r1 = (uint32_t)__shfl_xor((int)t1, 32, 64);
        union { uint32_t u[4]; s8v v; } uu;
        uu.u[0] = hi ? r0 : A0;
        uu.u[1] = hi ? r1 : A1;
        uu.u[2] = hi ? B0 : r0;
        uu.u[3] = hi ? B1 : r1;
#pragma unroll
        for (int jd = 0; jd < 4; ++jd) {
          const int rowd = 32 * jd + l31;
          const int slot = (2 * ks + hi) ^ (l31 & 7);
          s8v vf = *(const s8v*)&lVT[cur][rowd * 64 + slot * 8];
          yacc[jd] = __builtin_amdgcn_mfma_f32_32x32x16_bf16(uu.v, vf, yacc[jd], 0, 0, 0);
        }
      }
      __builtin_amdgcn_s_setprio(0);
      __syncthreads();
    }

    // ---- finalize: broadcast 1/l per C-row, write y (B,L,H*128) bf16 ----
    float inv = 1.0f / lrow;
#pragma unroll
    for (int r = 0; r < 16; ++r) {
      const int qloc = (r & 3) + 8 * (r >> 2) + 4 * hi;
      float ib = __shfl(inv, qloc, 64);
      const int qrow = q0 + qloc;
      size_t base = ((size_t)(b * 2048 + qrow)) * 2048 + h * 128 + l31;
#pragma unroll
      for (int jd = 0; jd < 4; ++jd)
        y[base + 32 * jd] = f2bf(yacc[jd][r] * ib);
    }
  }
}

extern "C" void kernel_launch(void* const* d_in, const int* in_sizes, int n_in,
                              void* d_out, int out_size, void* d_ws, size_t ws_size,
                              hipStream_t stream) {
  const float* x  = (const float*)d_in[0];
  const float* Wq = (const float*)d_in[1];
  const float* Wk = (const float*)d_in[2];
  const float* Wv = (const float*)d_in[3];
  const float* Wp = (const float*)d_in[4];
  const float* qg = (const float*)d_in[5];
  float* out = (float*)d_out;

  char* ws = (char*)d_ws;
  size_t off = 0;
  auto alloc = [&](size_t bytes) {
    void* p = ws + off;
    off += (bytes + 255) & ~(size_t)255;
    return p;
  };
  u16* x_bf  = (u16*)alloc((size_t)8192 * 2048 * 2);   // also reused as y_bf
  u16* wq_bf = (u16*)alloc((size_t)2048 * 2048 * 2);   // also reused as vt_bf
  u16* wk_bf = (u16*)alloc((size_t)512 * 2048 * 2);
  u16* wv_bf = (u16*)alloc((size_t)512 * 2048 * 2);
  u16* wp_bf = (u16*)alloc((size_t)2048 * 2048 * 2);
  u16* q_bf  = (u16*)alloc((size_t)4 * 16 * 2048 * 128 * 2);
  u16* k_bf  = (u16*)alloc((size_t)4 * 4 * 2048 * 128 * 2);
  u16* v_bf  = (u16*)alloc((size_t)4 * 4 * 2048 * 128 * 2);
  float* tab = (float*)alloc((size_t)2032 * 64 * 2 * 4);
  u16* y_bf  = x_bf;    // x dead after QKV GEMM
  u16* vt_bf = wq_bf;   // Wq dead after QKV GEMM (same size)

  cvt_bf16<<<2048, 256, 0, stream>>>((const float4*)x, (uint2*)x_bf, 8192 * 2048 / 4);
  cvt_bf16_w<<<1024, 256, 0, stream>>>((const float4*)Wq, (const float4*)Wk,
                                       (const float4*)Wv, (const float4*)Wp,
                                       (uint2*)wq_bf);   // wq|wk|wv|wp contiguous
  rope_table<<<(2032 * 64 + 255) / 256, 256, 0, stream>>>(tab, tab + 2032 * 64);

  gemm_nt<0><<<dim3(768), 512, 0, stream>>>(x_bf, wq_bf, wk_bf, wv_bf,
                                            q_bf, k_bf, v_bf, nullptr);
  norm_rope<<<2048, 256, 0, stream>>>(q_bf, qg, tab, tab + 2032 * 64); // q then k (contiguous)
  transpose_v<<<dim3(32, 2, 16), 256, 0, stream>>>(v_bf, vt_bf);
  attn<<<dim3(32, 16), 256, 0, stream>>>(q_bf, k_bf, vt_bf, y_bf);
  gemm_nt<1><<<dim3(512), 512, 0, stream>>>(y_bf, wp_bf, nullptr, nullptr,
                                            nullptr, nullptr, nullptr, out);
}

// Round 6
// 358.181 us; speedup vs baseline: 2.4882x; 1.0505x over previous
//
#include <hip/hip_runtime.h>
#include <stdint.h>

// Shapes (fixed): B=4 L=2048 D=2048 H=16 KVH=4 HD=128 M=16 T=2032
typedef unsigned short u16;
typedef short s8v __attribute__((ext_vector_type(8)));   // 8 bf16 (4 VGPR) MFMA frag
typedef float f4v __attribute__((ext_vector_type(4)));   // 16x16 MFMA accum
typedef float f16v __attribute__((ext_vector_type(16))); // 32x32 MFMA accum

typedef __attribute__((address_space(1))) char gchar;
typedef __attribute__((address_space(3))) char lchar;

static __device__ __forceinline__ u16 f2bf(float f) {
  uint32_t x = __float_as_uint(f);
  x += 0x7fffu + ((x >> 16) & 1u);            // RNE
  return (u16)(x >> 16);
}
static __device__ __forceinline__ float bf2f(u16 u) {
  return __uint_as_float(((uint32_t)u) << 16);
}
// async global->LDS, 16B per lane. LDS dest must be wave-linear (base + lane*16).
static __device__ __forceinline__ void gload_lds16(const void* g, void* l) {
  __builtin_amdgcn_global_load_lds((gchar*)(uintptr_t)g,
                                   (lchar*)(uint32_t)(uintptr_t)l, 16, 0, 0);
}

// ---------------- fp32 -> bf16 convert (vectorized) ----------------
__global__ __launch_bounds__(256) void cvt_bf16(const float4* __restrict__ src,
                                                uint2* __restrict__ dst, int n4) {
  int i = blockIdx.x * 256 + threadIdx.x;
  int st = gridDim.x * 256;
  for (; i < n4; i += st) {
    float4 v = src[i];
    uint2 o;
    o.x = (uint32_t)f2bf(v.x) | ((uint32_t)f2bf(v.y) << 16);
    o.y = (uint32_t)f2bf(v.z) | ((uint32_t)f2bf(v.w) << 16);
    dst[i] = o;
  }
}

// all 4 weight matrices in one launch; dst regions are contiguous in ws.
__global__ __launch_bounds__(256) void cvt_bf16_w(const float4* __restrict__ s0,
                                                  const float4* __restrict__ s1,
                                                  const float4* __restrict__ s2,
                                                  const float4* __restrict__ s3,
                                                  uint2* __restrict__ dst) {
  // boundaries in float4 units: wq 1048576 | wk 262144 | wv 262144 | wp 1048576
  int i = blockIdx.x * 256 + threadIdx.x;
  int st = gridDim.x * 256;
  for (; i < 2621440; i += st) {
    const float4* s;
    int off;
    if (i < 1048576)      { s = s0; off = i; }
    else if (i < 1310720) { s = s1; off = i - 1048576; }
    else if (i < 1572864) { s = s2; off = i - 1310720; }
    else                  { s = s3; off = i - 1572864; }
    float4 v = s[off];
    uint2 o;
    o.x = (uint32_t)f2bf(v.x) | ((uint32_t)f2bf(v.y) << 16);
    o.y = (uint32_t)f2bf(v.z) | ((uint32_t)f2bf(v.w) << 16);
    dst[i] = o;
  }
}

// ---------------- RoPE cos/sin table: [T=2032][64] ----------------
__global__ __launch_bounds__(256) void rope_table(float* __restrict__ tc,
                                                  float* __restrict__ ts) {
  int i = blockIdx.x * 256 + threadIdx.x;
  if (i >= 2032 * 64) return;
  int t = i >> 6, f = i & 63;
  float invf = 1.0f / powf(10000.0f, (float)f * (1.0f / 64.0f)); // accurate powf
  float ang = (float)t * invf;
  float s, c;
  sincosf(ang, &s, &c);                                           // accurate sincos
  tc[i] = c;
  ts[i] = s;
}

// ---------------- 256x128 BK=64 NT GEMM: C = A(MxK) @ W(NxK)^T ----------------
// 512 threads = 8 waves (4M x 2N), per-wave 64x64 output, BK=64 (32 MFMA + 16
// ds_read per wave per iteration -> per-iter barrier/drain overhead amortized
// 2x vs BK=32; R5 evidence: sync overhead, not LDS BW, limits this structure).
// 2-slot ring (96KB LDS), SAME verified barrier discipline as R5:
//   top: lgkmcnt(0)+sched_barrier+s_barrier  (closes iter t-1 reads -> WAR-safe)
//   stage(t+1) into slot (t+1)&1
//   s_waitcnt vmcnt(6) = own tile-t loads landed (counted, T4; never 0 in-loop)
//   s_barrier                                 (ALL waves' tile-t loads landed -> RAW)
//   16x ds_read_b128 (XOR slot swizzle: phys slot = s^(r&7); 2-way/16-lane-group
//   = free) + setprio'd 2x16 MFMA (T5)
// Grids even multiples of 256 CUs at 1 block/CU: mode0 768=3x256, mode1 512.
// MODE 0: QKV -> bf16 scattered to (B,heads,L,HD). MODE 1: proj -> fp32 out.
template <int MODE>
__global__ __launch_bounds__(512, 2) void gemm_nt(
    const u16* __restrict__ A, const u16* __restrict__ W0,
    const u16* __restrict__ W1, const u16* __restrict__ W2,
    u16* __restrict__ O0, u16* __restrict__ O1, u16* __restrict__ O2,
    float* __restrict__ OF) {
  __shared__ u16 lA[2][256 * 64];
  __shared__ u16 lB[2][128 * 64];
  const int tid = threadIdx.x;
  const int lane = tid & 63, wid = tid >> 6;
  const int wr = wid >> 1, wc = wid & 1;          // 4M x 2N waves
  const int l15 = lane & 15, l4 = lane >> 4;

  const int NB = (MODE == 0) ? 24 : 16;
  const int nwg = gridDim.x;
  const int bid = blockIdx.x;
  const int swz = (bid & 7) * (nwg >> 3) + (bid >> 3);  // XCD-chunked (nwg%8==0)
  const int bm = swz / NB, bn = swz % NB;
  const int m0 = bm * 256;

  const u16* Wt;
  int n0r;
  if constexpr (MODE == 0) {
    if (bn < 16)      { Wt = W0; n0r = bn * 128; }
    else if (bn < 20) { Wt = W1; n0r = (bn - 16) * 128; }
    else              { Wt = W2; n0r = (bn - 20) * 128; }
  } else {
    Wt = W0; n0r = bn * 128;
  }

  // row r = cidx>>3, slot s = cidx&7 (8B chunks); global src k-slot = s^(r&7)
  // (inverse swizzle at source, linear LDS dest, swizzled ds_read -> rule 21)
  auto stage = [&](int kt, int bsel) {
    const int kb = kt * 64;
#pragma unroll
    for (int c = 0; c < 4; ++c) {                 // A: 256x64 = 2048 chunks
      int cidx = tid + c * 512;
      int r = cidx >> 3, s = cidx & 7;
      gload_lds16(A + (size_t)(m0 + r) * 2048 + kb + ((s ^ (r & 7)) * 8),
                  &lA[bsel][cidx * 8]);
    }
#pragma unroll
    for (int c = 0; c < 2; ++c) {                 // B: 128x64 = 1024 chunks
      int cidx = tid + c * 512;
      int r = cidx >> 3, s = cidx & 7;
      gload_lds16(Wt + (size_t)(n0r + r) * 2048 + kb + ((s ^ (r & 7)) * 8),
                  &lB[bsel][cidx * 8]);
    }
  };
  // swizzled ds_read offset (u16 units) for logical row fr, 16B-slot s (0..7)
  auto swzoff = [&](int fr, int s) {
    return fr * 64 + (((s) ^ (fr & 7)) << 3);
  };

  const f4v Z4 = {0.f, 0.f, 0.f, 0.f};
  f4v acc[4][4];
#pragma unroll
  for (int i = 0; i < 4; i++)
#pragma unroll
    for (int j = 0; j < 4; j++) acc[i][j] = Z4;

  stage(0, 0);

  const int NT = 32;                 // 2048 / 64
  for (int t = 0; t < NT; ++t) {
    const int cur = t & 1;
    asm volatile("s_waitcnt lgkmcnt(0)" ::: "memory");
    __builtin_amdgcn_sched_barrier(0);
    asm volatile("s_barrier" ::: "memory");       // WAR: iter t-1 reads closed
    if (t + 1 < NT) {
      stage(t + 1, cur ^ 1);
      asm volatile("s_waitcnt vmcnt(6)" ::: "memory");   // own tile-t loads landed
    } else {
      asm volatile("s_waitcnt vmcnt(0)" ::: "memory");
    }
    asm volatile("s_barrier" ::: "memory");       // RAW: ALL waves' tile t landed

    const u16* pa = &lA[cur][0];
    const u16* pb = &lB[cur][0];
#pragma unroll
    for (int ks = 0; ks < 2; ++ks) {
      s8v afrg[4], bfrg[4];
#pragma unroll
      for (int i = 0; i < 4; ++i)
        afrg[i] = *(const s8v*)&pa[swzoff(wr * 64 + i * 16 + l15, ks * 4 + l4)];
#pragma unroll
      for (int j = 0; j < 4; ++j)
        bfrg[j] = *(const s8v*)&pb[swzoff(wc * 64 + j * 16 + l15, ks * 4 + l4)];
      __builtin_amdgcn_s_setprio(1);
#pragma unroll
      for (int i = 0; i < 4; ++i)
#pragma unroll
        for (int j = 0; j < 4; ++j)
          acc[i][j] = __builtin_amdgcn_mfma_f32_16x16x32_bf16(afrg[i], bfrg[j], acc[i][j], 0, 0, 0);
      __builtin_amdgcn_s_setprio(0);
    }
  }

  const int ncol0 = bn * 128 + wc * 64;           // 64-col stripe (head-half aligned)
  if constexpr (MODE == 0) {
    const int colg = ncol0;                       // within 3072 = Q|K|V
    u16* Ob; int hh, HX;
    if (colg < 2048)      { Ob = O0; hh = colg >> 7;          HX = 16; }
    else if (colg < 2560) { Ob = O1; hh = (colg - 2048) >> 7; HX = 4; }
    else                  { Ob = O2; hh = (colg - 2560) >> 7; HX = 4; }
    const int d0 = colg & 127;
#pragma unroll
    for (int i = 0; i < 4; i++)
#pragma unroll
      for (int r = 0; r < 4; r++) {
        int m = m0 + wr * 64 + i * 16 + l4 * 4 + r;
        int b = m >> 11, l = m & 2047;
        size_t base = ((size_t)(b * HX + hh) * 2048 + l) * 128 + d0;
#pragma unroll
        for (int j = 0; j < 4; j++)
          Ob[base + j * 16 + l15] = f2bf(acc[i][j][r]);
      }
  } else {
#pragma unroll
    for (int i = 0; i < 4; i++)
#pragma unroll
      for (int r = 0; r < 4; r++) {
        int m = m0 + wr * 64 + i * 16 + l4 * 4 + r;
#pragma unroll
        for (int j = 0; j < 4; j++)
          OF[(size_t)m * 2048 + ncol0 + j * 16 + l15] = acc[i][j][r];
      }
  }
}

// ---------------- RMSNorm + RoPE + gain, in place, one wave per 128-wide row
// q rows [0,131072) then k rows [131072,163840) — q_bf/k_bf contiguous in ws.
__global__ __launch_bounds__(256) void norm_rope(u16* __restrict__ buf,
                                                 const float* __restrict__ gain,
                                                 const float* __restrict__ tc,
                                                 const float* __restrict__ ts) {
  const int lane = threadIdx.x & 63;
  const int gw = blockIdx.x * 4 + (threadIdx.x >> 6);
  const int nw = gridDim.x * 4;
  for (int row = gw; row < 163840; row += nw) {
    int l = row & 2047;
    u16* p = buf + (size_t)row * 128;
    float x1 = bf2f(p[lane]);
    float x2 = bf2f(p[lane + 64]);
    float ss = x1 * x1 + x2 * x2;
#pragma unroll
    for (int off = 32; off > 0; off >>= 1) ss += __shfl_xor(ss, off, 64);
    float r = rsqrtf(ss * (1.0f / 128.0f) + 1.1920929e-07f);
    x1 *= r; x2 *= r;
    if (l >= 16) {
      int t = l - 16;
      float c = tc[t * 64 + lane], s = ts[t * 64 + lane];
      float o1 = x1 * c + x2 * s;
      float o2 = -x1 * s + x2 * c;
      x1 = o1; x2 = o2;
    }
    if (row < 131072) {            // q: apply per-head gain
      float g = gain[(row >> 11) & 15];
      x1 *= g; x2 *= g;
    }
    p[lane] = f2bf(x1);
    p[lane + 64] = f2bf(x2);
  }
}

// ---------------- V transpose: (bg,L,128) -> (bg,128,L), 64x64 LDS tiles, XOR swizzle
__global__ __launch_bounds__(256) void transpose_v(const u16* __restrict__ v,
                                                   u16* __restrict__ vt) {
  __shared__ u16 t[64][64];
  const int l0 = blockIdx.x * 64, d0 = blockIdx.y * 64, bg = blockIdx.z;
  const int tid = threadIdx.x;
#pragma unroll
  for (int it = 0; it < 2; ++it) {
    int lin = it * 256 + tid;
    int r = lin >> 3, cb = lin & 7;
    s8v val = *(const s8v*)&v[((bg * 2048 + l0 + r) * 128) + d0 + cb * 8];
    *(s8v*)&t[r][(cb ^ (r & 7)) * 8] = val;
  }
  __syncthreads();
#pragma unroll
  for (int it = 0; it < 2; ++it) {
    int lin = it * 256 + tid;
    int r2 = lin >> 3, c2 = (lin & 7) * 8;   // r2 = d idx, c2 = l idx
    s8v o;
#pragma unroll
    for (int j = 0; j < 8; ++j) {
      int rr = c2 + j, cc = r2;
      o[j] = (short)t[rr][(cc & 7) + 8 * ((cc >> 3) ^ (rr & 7))];
    }
    *(s8v*)&vt[((bg * 128 + d0 + r2) * 2048) + l0 + c2] = o;
  }
}

// ---------------- flash attention, 32x32 swapped-QK^T structure ----------------
// block = 4 waves = 4 q-heads of one KV group, 32 q-rows each; KVBLK=64.
// Causal pairing: block i handles q-tiles {i, 63-i} -> uniform 33-34 KV iters.
// Swapped QK^T (mfma(K,Q) -> C[kv][q]): lane owns q-row (lane&31); softmax fully
// in-register; P->PV A-frag rebuilt via bf16 pack + shfl_xor(32); defer-max THR=8.
__global__ __launch_bounds__(256, 2) void attn(const u16* __restrict__ q,
                                               const u16* __restrict__ k,
                                               const u16* __restrict__ vt,
                                               u16* __restrict__ y) {
  __shared__ u16 lK[2][64 * 128];   // row kv: 16 slots of 8 u16, slot s holds d-block s^(kv&7)
  __shared__ u16 lVT[2][128 * 64];  // row d:   8 slots of 8 u16, slot s holds kv-block s^(d&7)
  const int tid = threadIdx.x;
  const int lane = tid & 63, wid = tid >> 6;
  const int l31 = lane & 31, hi = lane >> 5;

  // XCD-aware remap: all 32 pair-blocks of one (b,g) land on one XCD (KV panel in L2)
  const int db = (int)blockIdx.y * 32 + (int)blockIdx.x;  // 0..511
  const int half = db >> 8, rem = db & 255;
  const int bg = (rem & 7) + 8 * half;                    // 0..15
  const int pairi = rem >> 3;                             // 0..31
  const int b = bg >> 2, g = bg & 3;
  const int h = g * 4 + wid;

  const u16* qh = q + (size_t)(b * 16 + h) * 2048 * 128;
  const u16* kb0 = k + (size_t)(b * 4 + g) * 2048 * 128;
  const u16* vtb0 = vt + (size_t)(b * 4 + g) * 128 * 2048;
  const float scale = 0.08838834764831845f;  // 1/sqrt(128)

  auto stage = [&](int t, int bufsel) {
    const int kv0 = t * 64;
#pragma unroll
    for (int it = 0; it < 4; ++it) {        // K tile 64x128 (16KB), swizzled source
      int lin = it * 256 + tid;
      int kj = lin >> 4, s = lin & 15;
      gload_lds16(kb0 + (size_t)(kv0 + kj) * 128 + ((s ^ (kj & 7)) * 8),
                  &lK[bufsel][lin * 8]);
    }
#pragma unroll
    for (int it = 0; it < 4; ++it) {        // VT tile 128x64 (16KB), swizzled source
      int lin = it * 256 + tid;
      int d = lin >> 3, s = lin & 7;
      gload_lds16(vtb0 + (size_t)d * 2048 + kv0 + ((s ^ (d & 7)) * 8),
                  &lVT[bufsel][lin * 8]);
    }
  };

  for (int ph = 0; ph < 2; ++ph) {
    const int qt = ph ? (63 - pairi) : pairi;
    const int q0 = qt * 32;
    const int nt = (q0 >> 6) + 1;           // KV tiles of 64 covering [0, q0+32)
    const int qabs = q0 + l31;

    // Q fragments: B-operand, col=q (lane&31), k = d = ks*16 + 8*hi + jj
    s8v qf[8];
#pragma unroll
    for (int ks = 0; ks < 8; ++ks)
      qf[ks] = *(const s8v*)&qh[(q0 + l31) * 128 + ks * 16 + hi * 8];

    f16v yacc[4];
#pragma unroll
    for (int j = 0; j < 4; ++j)
#pragma unroll
      for (int r = 0; r < 16; ++r) yacc[j][r] = 0.f;
    float mrow = -1e30f, lrow = 0.f;

    stage(0, 0);
    __syncthreads();

    for (int t = 0; t < nt; ++t) {
      const int cur = t & 1;
      if (t + 1 < nt) stage(t + 1, cur ^ 1);
      const int kv0 = t * 64;

      // ---- QK^T swapped: S^T[kv][q], two 32-kv chunks ----
      f16v s0a, s1a;
#pragma unroll
      for (int r = 0; r < 16; ++r) { s0a[r] = 0.f; s1a[r] = 0.f; }
      __builtin_amdgcn_s_setprio(1);
#pragma unroll
      for (int ks = 0; ks < 8; ++ks) {
        const int slot = (2 * ks + hi) ^ (l31 & 7);
        s8v kf0 = *(const s8v*)&lK[cur][(l31)*128 + slot * 8];
        s8v kf1 = *(const s8v*)&lK[cur][(32 + l31) * 128 + slot * 8];
        s0a = __builtin_amdgcn_mfma_f32_32x32x16_bf16(kf0, qf[ks], s0a, 0, 0, 0);
        s1a = __builtin_amdgcn_mfma_f32_32x32x16_bf16(kf1, qf[ks], s1a, 0, 0, 0);
      }
      __builtin_amdgcn_s_setprio(0);

      // ---- scale + causal mask + row max (in-register) ----
      const bool last = (t == nt - 1);
      float p0[16], p1[16];
      float pmax = -1e30f;
#pragma unroll
      for (int r = 0; r < 16; ++r) {
        const int kvloc = (r & 3) + 8 * (r >> 2) + 4 * hi;
        float v0 = s0a[r] * scale;
        float v1 = s1a[r] * scale;
        if (last) {
          if (kv0 + kvloc > qabs) v0 = -1e30f;
          if (kv0 + 32 + kvloc > qabs) v1 = -1e30f;
        }
        p0[r] = v0; p1[r] = v1;
        pmax = fmaxf(pmax, fmaxf(v0, v1));
      }
      pmax = fmaxf(pmax, __shfl_xor(pmax, 32, 64));

      // ---- defer-max (T13): rescale only when max grows past THR=8 ----
      if (!__all(pmax - mrow <= 8.0f)) {
        float mnew = fmaxf(mrow, pmax);
        float corr = __expf(mrow - mnew);
#pragma unroll
        for (int r = 0; r < 16; ++r) {
          const int qloc = (r & 3) + 8 * (r >> 2) + 4 * hi;
          float cb = __shfl(corr, qloc, 64);
          yacc[0][r] *= cb; yacc[1][r] *= cb; yacc[2][r] *= cb; yacc[3][r] *= cb;
        }
        lrow *= corr;
        mrow = mnew;
      }

      // ---- exp (bf16-rounded so denom matches MFMA numerator) + row sum ----
      float ps = 0.f;
#pragma unroll
      for (int r = 0; r < 16; ++r) {
        float e0 = bf2f(f2bf(__expf(p0[r] - mrow)));
        float e1 = bf2f(f2bf(__expf(p1[r] - mrow)));
        p0[r] = e0; p1[r] = e1;
        ps += e0 + e1;
      }
      ps += __shfl_xor(ps, 32, 64);
      lrow += ps;

      // ---- PV: rebuild A-frag (P rows = q) via pack + half-wave exchange ----
      __builtin_amdgcn_s_setprio(1);
#pragma unroll
      for (int ks = 0; ks < 4; ++ks) {
        const float* pc = (ks < 2) ? p0 : p1;
        const int rb = 8 * (ks & 1);
        uint32_t A0 = (uint32_t)f2bf(pc[rb + 0]) | ((uint32_t)f2bf(pc[rb + 1]) << 16);
        uint32_t A1 = (uint32_t)f2bf(pc[rb + 2]) | ((uint32_t)f2bf(pc[rb + 3]) << 16);
        uint32_t B0 = (uint32_t)f2bf(pc[rb + 4]) | ((uint32_t)f2bf(pc[rb + 5]) << 16);
        uint32_t B1 = (uint32_t)f2bf(pc[rb + 6]) | ((uint32_t)f2bf(pc[rb + 7]) << 16);
        uint32_t t0 = hi ? A0 : B0;
        uint32_t t1 = hi ? A1 : B1;
        uint32_t r0 = (uint32_t)__shfl_xor((int)t0, 32, 64);
        uint32_t r1 = (uint32_t)__shfl_xor((int)t1, 32, 64);
        union { uint32_t u[4]; s8v v; } uu;
        uu.u[0] = hi ? r0 : A0;
        uu.u[1] = hi ? r1 : A1;
        uu.u[2] = hi ? B0 : r0;
        uu.u[3] = hi ? B1 : r1;
#pragma unroll
        for (int jd = 0; jd < 4; ++jd) {
          const int rowd = 32 * jd + l31;
          const int slot = (2 * ks + hi) ^ (l31 & 7);
          s8v vf = *(const s8v*)&lVT[cur][rowd * 64 + slot * 8];
          yacc[jd] = __builtin_amdgcn_mfma_f32_32x32x16_bf16(uu.v, vf, yacc[jd], 0, 0, 0);
        }
      }
      __builtin_amdgcn_s_setprio(0);
      __syncthreads();
    }

    // ---- finalize: broadcast 1/l per C-row, write y (B,L,H*128) bf16 ----
    float inv = 1.0f / lrow;
#pragma unroll
    for (int r = 0; r < 16; ++r) {
      const int qloc = (r & 3) + 8 * (r >> 2) + 4 * hi;
      float ib = __shfl(inv, qloc, 64);
      const int qrow = q0 + qloc;
      size_t base = ((size_t)(b * 2048 + qrow)) * 2048 + h * 128 + l31;
#pragma unroll
      for (int jd = 0; jd < 4; ++jd)
        y[base + 32 * jd] = f2bf(yacc[jd][r] * ib);
    }
  }
}

extern "C" void kernel_launch(void* const* d_in, const int* in_sizes, int n_in,
                              void* d_out, int out_size, void* d_ws, size_t ws_size,
                              hipStream_t stream) {
  const float* x  = (const float*)d_in[0];
  const float* Wq = (const float*)d_in[1];
  const float* Wk = (const float*)d_in[2];
  const float* Wv = (const float*)d_in[3];
  const float* Wp = (const float*)d_in[4];
  const float* qg = (const float*)d_in[5];
  float* out = (float*)d_out;

  char* ws = (char*)d_ws;
  size_t off = 0;
  auto alloc = [&](size_t bytes) {
    void* p = ws + off;
    off += (bytes + 255) & ~(size_t)255;
    return p;
  };
  u16* x_bf  = (u16*)alloc((size_t)8192 * 2048 * 2);   // also reused as y_bf
  u16* wq_bf = (u16*)alloc((size_t)2048 * 2048 * 2);   // also reused as vt_bf
  u16* wk_bf = (u16*)alloc((size_t)512 * 2048 * 2);
  u16* wv_bf = (u16*)alloc((size_t)512 * 2048 * 2);
  u16* wp_bf = (u16*)alloc((size_t)2048 * 2048 * 2);
  u16* q_bf  = (u16*)alloc((size_t)4 * 16 * 2048 * 128 * 2);
  u16* k_bf  = (u16*)alloc((size_t)4 * 4 * 2048 * 128 * 2);
  u16* v_bf  = (u16*)alloc((size_t)4 * 4 * 2048 * 128 * 2);
  float* tab = (float*)alloc((size_t)2032 * 64 * 2 * 4);
  u16* y_bf  = x_bf;    // x dead after QKV GEMM
  u16* vt_bf = wq_bf;   // Wq dead after QKV GEMM (same size)

  cvt_bf16<<<2048, 256, 0, stream>>>((const float4*)x, (uint2*)x_bf, 8192 * 2048 / 4);
  cvt_bf16_w<<<1024, 256, 0, stream>>>((const float4*)Wq, (const float4*)Wk,
                                       (const float4*)Wv, (const float4*)Wp,
                                       (uint2*)wq_bf);   // wq|wk|wv|wp contiguous
  rope_table<<<(2032 * 64 + 255) / 256, 256, 0, stream>>>(tab, tab + 2032 * 64);

  gemm_nt<0><<<dim3(768), 512, 0, stream>>>(x_bf, wq_bf, wk_bf, wv_bf,
                                            q_bf, k_bf, v_bf, nullptr);
  norm_rope<<<2048, 256, 0, stream>>>(q_bf, qg, tab, tab + 2032 * 64); // q then k (contiguous)
  transpose_v<<<dim3(32, 2, 16), 256, 0, stream>>>(v_bf, vt_bf);
  attn<<<dim3(32, 16), 256, 0, stream>>>(q_bf, k_bf, vt_bf, y_bf);
  gemm_nt<1><<<dim3(512), 512, 0, stream>>>(y_bf, wp_bf, nullptr, nullptr,
                                            nullptr, nullptr, nullptr, out);
}

// Round 7
// 348.904 us; speedup vs baseline: 2.5543x; 1.0266x over previous
//
#include <hip/hip_runtime.h>
#include <stdint.h>

// Shapes (fixed): B=4 L=2048 D=2048 H=16 KVH=4 HD=128 M=16 T=2032
typedef unsigned short u16;
typedef short s8v __attribute__((ext_vector_type(8)));   // 8 bf16 (4 VGPR) MFMA frag
typedef float f4v __attribute__((ext_vector_type(4)));   // 16x16 MFMA accum
typedef float f16v __attribute__((ext_vector_type(16))); // 32x32 MFMA accum

typedef __attribute__((address_space(1))) char gchar;
typedef __attribute__((address_space(3))) char lchar;

static __device__ __forceinline__ u16 f2bf(float f) {
  uint32_t x = __float_as_uint(f);
  x += 0x7fffu + ((x >> 16) & 1u);            // RNE
  return (u16)(x >> 16);
}
static __device__ __forceinline__ float bf2f(u16 u) {
  return __uint_as_float(((uint32_t)u) << 16);
}
// async global->LDS, 16B per lane. LDS dest must be wave-linear (base + lane*16).
static __device__ __forceinline__ void gload_lds16(const void* g, void* l) {
  __builtin_amdgcn_global_load_lds((gchar*)(uintptr_t)g,
                                   (lchar*)(uint32_t)(uintptr_t)l, 16, 0, 0);
}

// ---------------- fp32 -> bf16 convert (vectorized) ----------------
__global__ __launch_bounds__(256) void cvt_bf16(const float4* __restrict__ src,
                                                uint2* __restrict__ dst, int n4) {
  int i = blockIdx.x * 256 + threadIdx.x;
  int st = gridDim.x * 256;
  for (; i < n4; i += st) {
    float4 v = src[i];
    uint2 o;
    o.x = (uint32_t)f2bf(v.x) | ((uint32_t)f2bf(v.y) << 16);
    o.y = (uint32_t)f2bf(v.z) | ((uint32_t)f2bf(v.w) << 16);
    dst[i] = o;
  }
}

// all 4 weight matrices in one launch; dst regions are contiguous in ws.
__global__ __launch_bounds__(256) void cvt_bf16_w(const float4* __restrict__ s0,
                                                  const float4* __restrict__ s1,
                                                  const float4* __restrict__ s2,
                                                  const float4* __restrict__ s3,
                                                  uint2* __restrict__ dst) {
  // boundaries in float4 units: wq 1048576 | wk 262144 | wv 262144 | wp 1048576
  int i = blockIdx.x * 256 + threadIdx.x;
  int st = gridDim.x * 256;
  for (; i < 2621440; i += st) {
    const float4* s;
    int off;
    if (i < 1048576)      { s = s0; off = i; }
    else if (i < 1310720) { s = s1; off = i - 1048576; }
    else if (i < 1572864) { s = s2; off = i - 1310720; }
    else                  { s = s3; off = i - 1572864; }
    float4 v = s[off];
    uint2 o;
    o.x = (uint32_t)f2bf(v.x) | ((uint32_t)f2bf(v.y) << 16);
    o.y = (uint32_t)f2bf(v.z) | ((uint32_t)f2bf(v.w) << 16);
    dst[i] = o;
  }
}

// ---------------- RoPE cos/sin table: [T=2032][64] ----------------
__global__ __launch_bounds__(256) void rope_table(float* __restrict__ tc,
                                                  float* __restrict__ ts) {
  int i = blockIdx.x * 256 + threadIdx.x;
  if (i >= 2032 * 64) return;
  int t = i >> 6, f = i & 63;
  float invf = 1.0f / powf(10000.0f, (float)f * (1.0f / 64.0f)); // accurate powf
  float ang = (float)t * invf;
  float s, c;
  sincosf(ang, &s, &c);                                           // accurate sincos
  tc[i] = c;
  ts[i] = s;
}

// ---------------- 256x128 BK=64 NT GEMM: C = A(MxK) @ W(NxK)^T ----------------
// 512 threads = 8 waves (4M x 2N), per-wave 64x64 output, BK=64 (32 MFMA + 16
// ds_read per wave per iteration -> per-iter barrier/drain overhead amortized
// 2x vs BK=32; R5 evidence: sync overhead, not LDS BW, limits this structure).
// 2-slot ring (96KB LDS), SAME verified barrier discipline as R5:
//   top: lgkmcnt(0)+sched_barrier+s_barrier  (closes iter t-1 reads -> WAR-safe)
//   stage(t+1) into slot (t+1)&1
//   s_waitcnt vmcnt(6) = own tile-t loads landed (counted, T4; never 0 in-loop)
//   s_barrier                                 (ALL waves' tile-t loads landed -> RAW)
//   16x ds_read_b128 (XOR slot swizzle: phys slot = s^(r&7); 2-way/16-lane-group
//   = free) + setprio'd 2x16 MFMA (T5)
// Grids even multiples of 256 CUs at 1 block/CU: mode0 768=3x256, mode1 512.
// MODE 0: QKV -> bf16 scattered to (B,heads,L,HD). MODE 1: proj -> fp32 out.
template <int MODE>
__global__ __launch_bounds__(512, 2) void gemm_nt(
    const u16* __restrict__ A, const u16* __restrict__ W0,
    const u16* __restrict__ W1, const u16* __restrict__ W2,
    u16* __restrict__ O0, u16* __restrict__ O1, u16* __restrict__ O2,
    float* __restrict__ OF) {
  __shared__ u16 lA[2][256 * 64];
  __shared__ u16 lB[2][128 * 64];
  const int tid = threadIdx.x;
  const int lane = tid & 63, wid = tid >> 6;
  const int wr = wid >> 1, wc = wid & 1;          // 4M x 2N waves
  const int l15 = lane & 15, l4 = lane >> 4;

  const int NB = (MODE == 0) ? 24 : 16;
  const int nwg = gridDim.x;
  const int bid = blockIdx.x;
  const int swz = (bid & 7) * (nwg >> 3) + (bid >> 3);  // XCD-chunked (nwg%8==0)
  const int bm = swz / NB, bn = swz % NB;
  const int m0 = bm * 256;

  const u16* Wt;
  int n0r;
  if constexpr (MODE == 0) {
    if (bn < 16)      { Wt = W0; n0r = bn * 128; }
    else if (bn < 20) { Wt = W1; n0r = (bn - 16) * 128; }
    else              { Wt = W2; n0r = (bn - 20) * 128; }
  } else {
    Wt = W0; n0r = bn * 128;
  }

  // row r = cidx>>3, slot s = cidx&7 (8B chunks); global src k-slot = s^(r&7)
  // (inverse swizzle at source, linear LDS dest, swizzled ds_read -> rule 21)
  auto stage = [&](int kt, int bsel) {
    const int kb = kt * 64;
#pragma unroll
    for (int c = 0; c < 4; ++c) {                 // A: 256x64 = 2048 chunks
      int cidx = tid + c * 512;
      int r = cidx >> 3, s = cidx & 7;
      gload_lds16(A + (size_t)(m0 + r) * 2048 + kb + ((s ^ (r & 7)) * 8),
                  &lA[bsel][cidx * 8]);
    }
#pragma unroll
    for (int c = 0; c < 2; ++c) {                 // B: 128x64 = 1024 chunks
      int cidx = tid + c * 512;
      int r = cidx >> 3, s = cidx & 7;
      gload_lds16(Wt + (size_t)(n0r + r) * 2048 + kb + ((s ^ (r & 7)) * 8),
                  &lB[bsel][cidx * 8]);
    }
  };
  // swizzled ds_read offset (u16 units) for logical row fr, 16B-slot s (0..7)
  auto swzoff = [&](int fr, int s) {
    return fr * 64 + (((s) ^ (fr & 7)) << 3);
  };

  const f4v Z4 = {0.f, 0.f, 0.f, 0.f};
  f4v acc[4][4];
#pragma unroll
  for (int i = 0; i < 4; i++)
#pragma unroll
    for (int j = 0; j < 4; j++) acc[i][j] = Z4;

  stage(0, 0);

  const int NT = 32;                 // 2048 / 64
  for (int t = 0; t < NT; ++t) {
    const int cur = t & 1;
    asm volatile("s_waitcnt lgkmcnt(0)" ::: "memory");
    __builtin_amdgcn_sched_barrier(0);
    asm volatile("s_barrier" ::: "memory");       // WAR: iter t-1 reads closed
    if (t + 1 < NT) {
      stage(t + 1, cur ^ 1);
      asm volatile("s_waitcnt vmcnt(6)" ::: "memory");   // own tile-t loads landed
    } else {
      asm volatile("s_waitcnt vmcnt(0)" ::: "memory");
    }
    asm volatile("s_barrier" ::: "memory");       // RAW: ALL waves' tile t landed

    const u16* pa = &lA[cur][0];
    const u16* pb = &lB[cur][0];
#pragma unroll
    for (int ks = 0; ks < 2; ++ks) {
      s8v afrg[4], bfrg[4];
#pragma unroll
      for (int i = 0; i < 4; ++i)
        afrg[i] = *(const s8v*)&pa[swzoff(wr * 64 + i * 16 + l15, ks * 4 + l4)];
#pragma unroll
      for (int j = 0; j < 4; ++j)
        bfrg[j] = *(const s8v*)&pb[swzoff(wc * 64 + j * 16 + l15, ks * 4 + l4)];
      __builtin_amdgcn_s_setprio(1);
#pragma unroll
      for (int i = 0; i < 4; ++i)
#pragma unroll
        for (int j = 0; j < 4; ++j)
          acc[i][j] = __builtin_amdgcn_mfma_f32_16x16x32_bf16(afrg[i], bfrg[j], acc[i][j], 0, 0, 0);
      __builtin_amdgcn_s_setprio(0);
    }
  }

  const int ncol0 = bn * 128 + wc * 64;           // 64-col stripe (head-half aligned)
  if constexpr (MODE == 0) {
    const int colg = ncol0;                       // within 3072 = Q|K|V
    u16* Ob; int hh, HX;
    if (colg < 2048)      { Ob = O0; hh = colg >> 7;          HX = 16; }
    else if (colg < 2560) { Ob = O1; hh = (colg - 2048) >> 7; HX = 4; }
    else                  { Ob = O2; hh = (colg - 2560) >> 7; HX = 4; }
    const int d0 = colg & 127;
#pragma unroll
    for (int i = 0; i < 4; i++)
#pragma unroll
      for (int r = 0; r < 4; r++) {
        int m = m0 + wr * 64 + i * 16 + l4 * 4 + r;
        int b = m >> 11, l = m & 2047;
        size_t base = ((size_t)(b * HX + hh) * 2048 + l) * 128 + d0;
#pragma unroll
        for (int j = 0; j < 4; j++)
          Ob[base + j * 16 + l15] = f2bf(acc[i][j][r]);
      }
  } else {
#pragma unroll
    for (int i = 0; i < 4; i++)
#pragma unroll
      for (int r = 0; r < 4; r++) {
        int m = m0 + wr * 64 + i * 16 + l4 * 4 + r;
#pragma unroll
        for (int j = 0; j < 4; j++)
          OF[(size_t)m * 2048 + ncol0 + j * 16 + l15] = acc[i][j][r];
      }
  }
}

// ---------------- RMSNorm + RoPE + gain, in place, one wave per 128-wide row
// q rows [0,131072) then k rows [131072,163840) — q_bf/k_bf contiguous in ws.
// q additionally absorbs 1/sqrt(128) * log2(e) so attn's QK^T lands directly
// in the exp2 domain (saves 64 VALU muls per tile per wave in attn).
__global__ __launch_bounds__(256) void norm_rope(u16* __restrict__ buf,
                                                 const float* __restrict__ gain,
                                                 const float* __restrict__ tc,
                                                 const float* __restrict__ ts) {
  const int lane = threadIdx.x & 63;
  const int gw = blockIdx.x * 4 + (threadIdx.x >> 6);
  const int nw = gridDim.x * 4;
  for (int row = gw; row < 163840; row += nw) {
    int l = row & 2047;
    u16* p = buf + (size_t)row * 128;
    float x1 = bf2f(p[lane]);
    float x2 = bf2f(p[lane + 64]);
    float ss = x1 * x1 + x2 * x2;
#pragma unroll
    for (int off = 32; off > 0; off >>= 1) ss += __shfl_xor(ss, off, 64);
    float r = rsqrtf(ss * (1.0f / 128.0f) + 1.1920929e-07f);
    x1 *= r; x2 *= r;
    if (l >= 16) {
      int t = l - 16;
      float c = tc[t * 64 + lane], s = ts[t * 64 + lane];
      float o1 = x1 * c + x2 * s;
      float o2 = -x1 * s + x2 * c;
      x1 = o1; x2 = o2;
    }
    if (row < 131072) {            // q: gain * 1/sqrt(128) * log2(e)
      float g = gain[(row >> 11) & 15] *
                (0.08838834764831845f * 1.4426950408889634f);
      x1 *= g; x2 *= g;
    }
    p[lane] = f2bf(x1);
    p[lane + 64] = f2bf(x2);
  }
}

// ---------------- V transpose: (bg,L,128) -> (bg,128,L), 64x64 LDS tiles, XOR swizzle
__global__ __launch_bounds__(256) void transpose_v(const u16* __restrict__ v,
                                                   u16* __restrict__ vt) {
  __shared__ u16 t[64][64];
  const int l0 = blockIdx.x * 64, d0 = blockIdx.y * 64, bg = blockIdx.z;
  const int tid = threadIdx.x;
#pragma unroll
  for (int it = 0; it < 2; ++it) {
    int lin = it * 256 + tid;
    int r = lin >> 3, cb = lin & 7;
    s8v val = *(const s8v*)&v[((bg * 2048 + l0 + r) * 128) + d0 + cb * 8];
    *(s8v*)&t[r][(cb ^ (r & 7)) * 8] = val;
  }
  __syncthreads();
#pragma unroll
  for (int it = 0; it < 2; ++it) {
    int lin = it * 256 + tid;
    int r2 = lin >> 3, c2 = (lin & 7) * 8;   // r2 = d idx, c2 = l idx
    s8v o;
#pragma unroll
    for (int j = 0; j < 8; ++j) {
      int rr = c2 + j, cc = r2;
      o[j] = (short)t[rr][(cc & 7) + 8 * ((cc >> 3) ^ (rr & 7))];
    }
    *(s8v*)&vt[((bg * 128 + d0 + r2) * 2048) + l0 + c2] = o;
  }
}

// ---------------- flash attention, 32x32 swapped-QK^T structure ----------------
// block = 4 waves = 4 q-heads of one KV group, 32 q-rows each; KVBLK=64.
// Causal pairing: block i handles q-tiles {i, 63-i} -> uniform 33-34 KV iters.
// Swapped QK^T (mfma(K,Q) -> C[kv][q]): lane owns q-row (lane&31); softmax fully
// in-register IN THE EXP2 DOMAIN (scale*log2e folded into q); P packed to bf16
// once via v_cvt_pk_bf16_f32 (16 instrs vs 64 scalar RNE); denominator = fp32
// sum of unrounded exp (<=0.4% rel vs rounded numerator, within threshold
// headroom); P->PV A-frag via pack + shfl_xor(32); defer-max THR=8*log2e.
__global__ __launch_bounds__(256, 2) void attn(const u16* __restrict__ q,
                                               const u16* __restrict__ k,
                                               const u16* __restrict__ vt,
                                               u16* __restrict__ y) {
  __shared__ u16 lK[2][64 * 128];   // row kv: 16 slots of 8 u16, slot s holds d-block s^(kv&7)
  __shared__ u16 lVT[2][128 * 64];  // row d:   8 slots of 8 u16, slot s holds kv-block s^(d&7)
  const int tid = threadIdx.x;
  const int lane = tid & 63, wid = tid >> 6;
  const int l31 = lane & 31, hi = lane >> 5;

  // XCD-aware remap: all 32 pair-blocks of one (b,g) land on one XCD (KV panel in L2)
  const int db = (int)blockIdx.y * 32 + (int)blockIdx.x;  // 0..511
  const int half = db >> 8, rem = db & 255;
  const int bg = (rem & 7) + 8 * half;                    // 0..15
  const int pairi = rem >> 3;                             // 0..31
  const int b = bg >> 2, g = bg & 3;
  const int h = g * 4 + wid;

  const u16* qh = q + (size_t)(b * 16 + h) * 2048 * 128;
  const u16* kb0 = k + (size_t)(b * 4 + g) * 2048 * 128;
  const u16* vtb0 = vt + (size_t)(b * 4 + g) * 128 * 2048;

  auto stage = [&](int t, int bufsel) {
    const int kv0 = t * 64;
#pragma unroll
    for (int it = 0; it < 4; ++it) {        // K tile 64x128 (16KB), swizzled source
      int lin = it * 256 + tid;
      int kj = lin >> 4, s = lin & 15;
      gload_lds16(kb0 + (size_t)(kv0 + kj) * 128 + ((s ^ (kj & 7)) * 8),
                  &lK[bufsel][lin * 8]);
    }
#pragma unroll
    for (int it = 0; it < 4; ++it) {        // VT tile 128x64 (16KB), swizzled source
      int lin = it * 256 + tid;
      int d = lin >> 3, s = lin & 7;
      gload_lds16(vtb0 + (size_t)d * 2048 + kv0 + ((s ^ (d & 7)) * 8),
                  &lVT[bufsel][lin * 8]);
    }
  };

  for (int ph = 0; ph < 2; ++ph) {
    const int qt = ph ? (63 - pairi) : pairi;
    const int q0 = qt * 32;
    const int nt = (q0 >> 6) + 1;           // KV tiles of 64 covering [0, q0+32)
    const int qabs = q0 + l31;

    // Q fragments: B-operand, col=q (lane&31), k = d = ks*16 + 8*hi + jj
    s8v qf[8];
#pragma unroll
    for (int ks = 0; ks < 8; ++ks)
      qf[ks] = *(const s8v*)&qh[(q0 + l31) * 128 + ks * 16 + hi * 8];

    f16v yacc[4];
#pragma unroll
    for (int j = 0; j < 4; ++j)
#pragma unroll
      for (int r = 0; r < 16; ++r) yacc[j][r] = 0.f;
    float mrow = -1e30f, lrow = 0.f;

    stage(0, 0);
    __syncthreads();

    for (int t = 0; t < nt; ++t) {
      const int cur = t & 1;
      if (t + 1 < nt) stage(t + 1, cur ^ 1);
      const int kv0 = t * 64;

      // ---- QK^T swapped: S^T[kv][q] in exp2 domain, two 32-kv chunks ----
      f16v s0a, s1a;
#pragma unroll
      for (int r = 0; r < 16; ++r) { s0a[r] = 0.f; s1a[r] = 0.f; }
      __builtin_amdgcn_s_setprio(1);
#pragma unroll
      for (int ks = 0; ks < 8; ++ks) {
        const int slot = (2 * ks + hi) ^ (l31 & 7);
        s8v kf0 = *(const s8v*)&lK[cur][(l31)*128 + slot * 8];
        s8v kf1 = *(const s8v*)&lK[cur][(32 + l31) * 128 + slot * 8];
        s0a = __builtin_amdgcn_mfma_f32_32x32x16_bf16(kf0, qf[ks], s0a, 0, 0, 0);
        s1a = __builtin_amdgcn_mfma_f32_32x32x16_bf16(kf1, qf[ks], s1a, 0, 0, 0);
      }
      __builtin_amdgcn_s_setprio(0);

      // ---- causal mask + row max (in-register; scores already log2-scaled) ----
      const bool last = (t == nt - 1);
      float p0[16], p1[16];
      float pmax = -1e30f;
#pragma unroll
      for (int r = 0; r < 16; ++r) {
        const int kvloc = (r & 3) + 8 * (r >> 2) + 4 * hi;
        float v0 = s0a[r];
        float v1 = s1a[r];
        if (last) {
          if (kv0 + kvloc > qabs) v0 = -1e30f;
          if (kv0 + 32 + kvloc > qabs) v1 = -1e30f;
        }
        p0[r] = v0; p1[r] = v1;
        pmax = fmaxf(pmax, fmaxf(v0, v1));
      }
      pmax = fmaxf(pmax, __shfl_xor(pmax, 32, 64));

      // ---- defer-max (T13): THR = 8*log2e in exp2 domain ----
      if (!__all(pmax - mrow <= 11.541560327111707f)) {
        float mnew = fmaxf(mrow, pmax);
        float corr = __builtin_amdgcn_exp2f(mrow - mnew);
#pragma unroll
        for (int r = 0; r < 16; ++r) {
          const int qloc = (r & 3) + 8 * (r >> 2) + 4 * hi;
          float cb = __shfl(corr, qloc, 64);
          yacc[0][r] *= cb; yacc[1][r] *= cb; yacc[2][r] *= cb; yacc[3][r] *= cb;
        }
        lrow *= corr;
        mrow = mnew;
      }

      // ---- exp2 + fp32 row sum (denominator unrounded; see header note) ----
      float ps = 0.f;
#pragma unroll
      for (int r = 0; r < 16; ++r) {
        float e0 = __builtin_amdgcn_exp2f(p0[r] - mrow);
        float e1 = __builtin_amdgcn_exp2f(p1[r] - mrow);
        p0[r] = e0; p1[r] = e1;
        ps += e0 + e1;
      }
      ps += __shfl_xor(ps, 32, 64);
      lrow += ps;

      // ---- PV: pack P once (v_cvt_pk_bf16_f32) + half-wave exchange ----
      __builtin_amdgcn_s_setprio(1);
#pragma unroll
      for (int ks = 0; ks < 4; ++ks) {
        const float* pc = (ks < 2) ? p0 : p1;
        const int rb = 8 * (ks & 1);
        uint32_t A0, A1, B0, B1;
        asm("v_cvt_pk_bf16_f32 %0, %1, %2" : "=v"(A0) : "v"(pc[rb + 0]), "v"(pc[rb + 1]));
        asm("v_cvt_pk_bf16_f32 %0, %1, %2" : "=v"(A1) : "v"(pc[rb + 2]), "v"(pc[rb + 3]));
        asm("v_cvt_pk_bf16_f32 %0, %1, %2" : "=v"(B0) : "v"(pc[rb + 4]), "v"(pc[rb + 5]));
        asm("v_cvt_pk_bf16_f32 %0, %1, %2" : "=v"(B1) : "v"(pc[rb + 6]), "v"(pc[rb + 7]));
        uint32_t t0 = hi ? A0 : B0;
        uint32_t t1 = hi ? A1 : B1;
        uint32_t r0 = (uint32_t)__shfl_xor((int)t0, 32, 64);
        uint32_t r1 = (uint32_t)__shfl_xor((int)t1, 32, 64);
        union { uint32_t u[4]; s8v v; } uu;
        uu.u[0] = hi ? r0 : A0;
        uu.u[1] = hi ? r1 : A1;
        uu.u[2] = hi ? B0 : r0;
        uu.u[3] = hi ? B1 : r1;
#pragma unroll
        for (int jd = 0; jd < 4; ++jd) {
          const int rowd = 32 * jd + l31;
          const int slot = (2 * ks + hi) ^ (l31 & 7);
          s8v vf = *(const s8v*)&lVT[cur][rowd * 64 + slot * 8];
          yacc[jd] = __builtin_amdgcn_mfma_f32_32x32x16_bf16(uu.v, vf, yacc[jd], 0, 0, 0);
        }
      }
      __builtin_amdgcn_s_setprio(0);
      __syncthreads();
    }

    // ---- finalize: broadcast 1/l per C-row, write y (B,L,H*128) bf16 ----
    float inv = 1.0f / lrow;
#pragma unroll
    for (int r = 0; r < 16; ++r) {
      const int qloc = (r & 3) + 8 * (r >> 2) + 4 * hi;
      float ib = __shfl(inv, qloc, 64);
      const int qrow = q0 + qloc;
      size_t base = ((size_t)(b * 2048 + qrow)) * 2048 + h * 128 + l31;
#pragma unroll
      for (int jd = 0; jd < 4; ++jd)
        y[base + 32 * jd] = f2bf(yacc[jd][r] * ib);
    }
  }
}

extern "C" void kernel_launch(void* const* d_in, const int* in_sizes, int n_in,
                              void* d_out, int out_size, void* d_ws, size_t ws_size,
                              hipStream_t stream) {
  const float* x  = (const float*)d_in[0];
  const float* Wq = (const float*)d_in[1];
  const float* Wk = (const float*)d_in[2];
  const float* Wv = (const float*)d_in[3];
  const float* Wp = (const float*)d_in[4];
  const float* qg = (const float*)d_in[5];
  float* out = (float*)d_out;

  char* ws = (char*)d_ws;
  size_t off = 0;
  auto alloc = [&](size_t bytes) {
    void* p = ws + off;
    off += (bytes + 255) & ~(size_t)255;
    return p;
  };
  u16* x_bf  = (u16*)alloc((size_t)8192 * 2048 * 2);   // also reused as y_bf
  u16* wq_bf = (u16*)alloc((size_t)2048 * 2048 * 2);   // also reused as vt_bf
  u16* wk_bf = (u16*)alloc((size_t)512 * 2048 * 2);
  u16* wv_bf = (u16*)alloc((size_t)512 * 2048 * 2);
  u16* wp_bf = (u16*)alloc((size_t)2048 * 2048 * 2);
  u16* q_bf  = (u16*)alloc((size_t)4 * 16 * 2048 * 128 * 2);
  u16* k_bf  = (u16*)alloc((size_t)4 * 4 * 2048 * 128 * 2);
  u16* v_bf  = (u16*)alloc((size_t)4 * 4 * 2048 * 128 * 2);
  float* tab = (float*)alloc((size_t)2032 * 64 * 2 * 4);
  u16* y_bf  = x_bf;    // x dead after QKV GEMM
  u16* vt_bf = wq_bf;   // Wq dead after QKV GEMM (same size)

  cvt_bf16<<<2048, 256, 0, stream>>>((const float4*)x, (uint2*)x_bf, 8192 * 2048 / 4);
  cvt_bf16_w<<<1024, 256, 0, stream>>>((const float4*)Wq, (const float4*)Wk,
                                       (const float4*)Wv, (const float4*)Wp,
                                       (uint2*)wq_bf);   // wq|wk|wv|wp contiguous
  rope_table<<<(2032 * 64 + 255) / 256, 256, 0, stream>>>(tab, tab + 2032 * 64);

  gemm_nt<0><<<dim3(768), 512, 0, stream>>>(x_bf, wq_bf, wk_bf, wv_bf,
                                            q_bf, k_bf, v_bf, nullptr);
  norm_rope<<<2048, 256, 0, stream>>>(q_bf, qg, tab, tab + 2032 * 64); // q then k (contiguous)
  transpose_v<<<dim3(32, 2, 16), 256, 0, stream>>>(v_bf, vt_bf);
  attn<<<dim3(32, 16), 256, 0, stream>>>(q_bf, k_bf, vt_bf, y_bf);
  gemm_nt<1><<<dim3(512), 512, 0, stream>>>(y_bf, wp_bf, nullptr, nullptr,
                                            nullptr, nullptr, nullptr, out);
}